// Round 1
// baseline (521.504 us; speedup 1.0000x reference)
//
#include <hip/hip_runtime.h>
#include <math.h>

#define BB 64
#define HH 512
#define VV 50000
#define LL 400
#define MM 128
#define DD 64
#define HC 260
#define EPSF 1e-8f

typedef __attribute__((ext_vector_type(8))) short bf16x8;
typedef __attribute__((ext_vector_type(4))) float f32x4;

__device__ __forceinline__ float sigmoidf(float x){ return 1.0f/(1.0f+expf(-x)); }
__device__ __forceinline__ unsigned short bf16_rne(float f){
  unsigned u = __float_as_uint(f);
  return (unsigned short)((u + 0x7fffu + ((u >> 16) & 1u)) >> 16);
}
__device__ __forceinline__ float wave_max(float v){
  #pragma unroll
  for(int o=32;o;o>>=1) v = fmaxf(v, __shfl_xor(v,o));
  return v;
}
__device__ __forceinline__ float wave_sum(float v){
  #pragma unroll
  for(int o=32;o;o>>=1) v += __shfl_xor(v,o);
  return v;
}

// ---------------- embed + concat builders ----------------
__global__ void k_embed(const int* __restrict__ ids, const float* __restrict__ emb,
                        const float* __restrict__ h0, float* __restrict__ xcat1,
                        float* __restrict__ xcat2){
  int idx = blockIdx.x*256 + threadIdx.x;           // 64*512
  if (idx >= BB*HH) return;
  int b = idx >> 9, h = idx & 511;
  float e = emb[(long)ids[b]*HH + h];
  xcat1[b*1024 + h] = e;
  xcat2[b*1024 + h] = e;
  xcat1[b*1024 + 512 + h] = h0[idx];
}

// ---------------- wave-per-output GEMV: C[b,n] = (A[+A2])[b,:] . W[n,:] ----------------
template<int NB, int FUSE>
__global__ __launch_bounds__(256) void k_gemv(const float* __restrict__ A,
                                              const float* __restrict__ A2,
                                              const float* __restrict__ W,
                                              const float* __restrict__ b1,
                                              float* __restrict__ C,
                                              int K, int N, int ldc){
  int b = blockIdx.y;
  int wid = threadIdx.x >> 6, lane = threadIdx.x & 63;
  int n = blockIdx.x*4 + wid;
  if (n >= N) return;
  const float4* A4  = (const float4*)(A + (long)b*K);
  const float4* A24 = (const float4*)(A2 + (long)b*K);
  const float4* W4  = (const float4*)(W + (long)n*K);
  int K4 = K >> 2;
  float acc = 0.f;
  for (int k = lane; k < K4; k += 64){
    float4 a = A4[k];
    if (FUSE){ float4 a2 = A24[k]; a.x+=a2.x; a.y+=a2.y; a.z+=a2.z; a.w+=a2.w; }
    float4 w = W4[k];
    acc += a.x*w.x + a.y*w.y + a.z*w.z + a.w*w.w;
  }
  acc = wave_sum(acc);
  if (lane == 0){
    if (NB) acc += b1[n];
    C[(long)b*ldc + n] = acc;
  }
}

// ---------------- new_coverage = coverage + ia ----------------
__global__ void k_cov(const float* __restrict__ cov, const float* __restrict__ ia,
                      float* __restrict__ out){
  int idx = blockIdx.x*256 + threadIdx.x;     // 25600
  if (idx >= BB*LL) return;
  out[idx] = cov[idx] + ia[idx];
}

// ---------------- aw = softmax(tc+ia+ts) over L ----------------
__global__ __launch_bounds__(256) void k_softmax_aw(const float* __restrict__ ia,
                                                    const float* __restrict__ ts,
                                                    const float* __restrict__ tc,
                                                    float* __restrict__ aw){
  int b = blockIdx.x, t = threadIdx.x;
  int i0 = t, i1 = t + 256;
  float x0 = ia[b*LL+i0] + ts[b*LL+i0] + tc[b*LL+i0];
  float x1 = (i1 < LL) ? (ia[b*LL+i1] + ts[b*LL+i1] + tc[b*LL+i1]) : -INFINITY;
  __shared__ float sm[4], ss[4];
  float m = wave_max(fmaxf(x0, x1));
  if ((t & 63) == 0) sm[t>>6] = m;
  __syncthreads();
  m = fmaxf(fmaxf(sm[0], sm[1]), fmaxf(sm[2], sm[3]));
  float e0 = expf(x0 - m);
  float e1 = (i1 < LL) ? expf(x1 - m) : 0.0f;
  float s = wave_sum(e0 + e1);
  if ((t & 63) == 0) ss[t>>6] = s;
  __syncthreads();
  float tot = ss[0] + ss[1] + ss[2] + ss[3];
  float inv = 1.0f / tot;
  aw[b*LL + i0] = e0 * inv;
  if (i1 < LL) aw[b*LL + i1] = e1 * inv;
}

// ---------------- attn_applied partials: grid (64 b, 16 l-chunks of 25) ----------------
__global__ __launch_bounds__(256) void k_attn_part(const float* __restrict__ aw,
                                                   const float* __restrict__ enc,
                                                   float* __restrict__ part){
  int b = blockIdx.x, lc = blockIdx.y, t = threadIdx.x;
  const float* awb = aw + b*LL + lc*25;
  const float* eb  = enc + ((long)b*LL + lc*25)*HH;
  float a0 = 0.f, a1 = 0.f;
  for (int l = 0; l < 25; l++){
    float a = awb[l];
    a0 += a * eb[(long)l*HH + t];
    a1 += a * eb[(long)l*HH + t + 256];
  }
  part[((b*16 + lc) << 9) + t]       = a0;
  part[((b*16 + lc) << 9) + t + 256] = a1;
}

__global__ void k_attn_reduce(const float* __restrict__ part, float* __restrict__ xcat2){
  int idx = blockIdx.x*256 + threadIdx.x;       // 64*512
  if (idx >= BB*HH) return;
  int b = idx >> 9, h = idx & 511;
  float s = 0.f;
  #pragma unroll
  for (int lc = 0; lc < 16; lc++) s += part[((b*16 + lc) << 9) + h];
  xcat2[b*1024 + 512 + h] = s;
}

// ---------------- pre GEMV, K-split: grid (16 n-quads, 64 b, which*8+chunk) ----------------
// pre = [h0 | mem] @ {r,w}pre_W^T ; K=8704 split into 8 chunks of 1088.
__global__ __launch_bounds__(256) void k_pre_gemv(const float* __restrict__ h0,
                                                  const float* __restrict__ mem,
                                                  const float* __restrict__ rW,
                                                  const float* __restrict__ wW,
                                                  float* __restrict__ part){
  int wid = threadIdx.x >> 6, lane = threadIdx.x & 63;
  int n = blockIdx.x*4 + wid;        // 0..63
  int b = blockIdx.y;
  int z = blockIdx.z;                // which*8 + chunk
  int which = z >> 3, chunk = z & 7;
  const float* W = which ? wW : rW;
  const float4* W4 = (const float4*)(W + (long)n*8704 + chunk*1088);
  const float4* H4 = (const float4*)(h0 + (long)b*HH);
  const float4* M4 = (const float4*)(mem + (long)b*8192 + (chunk*1088 - 512));
  float acc = 0.f;
  #pragma unroll
  for (int i = 0; i < 5; i++){
    int k4 = lane + i*64;            // float4 index within chunk (272 total)
    if (k4 < 272){
      int kg4 = chunk*272 + k4;      // global float4 index
      float4 a = (kg4 < 128) ? H4[kg4] : M4[k4];
      float4 w = W4[k4];
      acc += a.x*w.x + a.y*w.y + a.z*w.z + a.w*w.w;
    }
  }
  acc = wave_sum(acc);
  if (lane == 0) part[z*4096 + b*64 + n] = acc;
}

__global__ void k_pre_reduce(const float* __restrict__ part, const float* __restrict__ rb,
                             const float* __restrict__ wb, float* __restrict__ pre_r,
                             float* __restrict__ pre_w){
  int idx = blockIdx.x*256 + threadIdx.x;     // 8192
  if (idx >= 8192) return;
  int which = idx >> 12;
  int r = idx & 4095;
  float s = 0.f;
  #pragma unroll
  for (int c = 0; c < 8; c++) s += part[((which<<3)+c)*4096 + r];
  int n = r & 63;
  s += which ? wb[n] : rb[n];
  (which ? pre_w : pre_r)[r] = s;
}

// ---------------- fused gates GEMV for r/w heads: grid (260, 64, 2) ----------------
__global__ __launch_bounds__(256) void k_gates_rw(const float* __restrict__ pre_r,
    const float* __restrict__ pre_w, const float* __restrict__ read_h,
    const float* __restrict__ write_h,
    const float* __restrict__ rWih, const float* __restrict__ rWhh,
    const float* __restrict__ rbih, const float* __restrict__ rbhh,
    const float* __restrict__ wWih, const float* __restrict__ wWhh,
    const float* __restrict__ wbih, const float* __restrict__ wbhh,
    float* __restrict__ g_r, float* __restrict__ g_w){
  int which = blockIdx.z;
  int b = blockIdx.y;
  int wid = threadIdx.x >> 6, lane = threadIdx.x & 63;
  int n = blockIdx.x*4 + wid;     // < 1040
  const float* pre = which ? pre_w : pre_r;     // (64,64)
  const float* hh  = which ? write_h : read_h;  // (64,260)
  const float* Wih = which ? wWih : rWih;       // (1040,64)
  const float* Whh = which ? wWhh : rWhh;       // (1040,260)
  float acc = pre[b*64 + lane] * Wih[n*64 + lane];
  const float* hb = hh + b*HC;
  const float* wr = Whh + (long)n*HC;
  #pragma unroll
  for (int i = 0; i < 5; i++){
    int k = lane + i*64;
    if (k < HC) acc += hb[k]*wr[k];
  }
  acc = wave_sum(acc);
  if (lane == 0){
    acc += (which ? wbih : rbih)[n] + (which ? wbhh : rbhh)[n];
    (which ? g_w : g_r)[(long)b*4*HC + n] = acc;
  }
}

// ---------------- fused r+w LSTM elementwise ----------------
__global__ void k_lstm_rw(const float* __restrict__ g_r, const float* __restrict__ g_w,
                          const float* __restrict__ read_c, const float* __restrict__ write_c,
                          float* __restrict__ rh, float* __restrict__ wh){
  int idx = blockIdx.x*256 + threadIdx.x;    // 2*64*260 = 33280
  if (idx >= 2*BB*HC) return;
  int which = idx >= BB*HC;
  int r = which ? idx - BB*HC : idx;
  int b = r / HC, j = r - b*HC;
  const float* g = (which ? g_w : g_r) + (long)b*4*HC;
  float c2 = sigmoidf(g[HC + j]) * (which ? write_c : read_c)[r]
           + sigmoidf(g[j]) * tanhf(g[2*HC + j]);
  (which ? wh : rh)[r] = sigmoidf(g[3*HC + j]) * tanhf(c2);
}

// ---------------- addressing: grid (64, 2), 128 threads ----------------
__global__ __launch_bounds__(128) void k_address(const float* __restrict__ rh,
                                                 const float* __restrict__ whv,
                                                 const float* __restrict__ rheads,
                                                 const float* __restrict__ wheads,
                                                 const float* __restrict__ mem,
                                                 float* __restrict__ rwout,
                                                 float* __restrict__ wwout){
  int which = blockIdx.y;
  int b = blockIdx.x, m = threadIdx.x;
  const float* hc = which ? whv : rh;
  const float* heads0 = which ? wheads : rheads;
  float* wout = which ? wwout : rwout;
  const float* mr = mem + ((long)b*MM + m)*DD;
  float s = 0.f, q = 0.f;
  #pragma unroll 8
  for (int d = 0; d < DD; d++){ float v = mr[d]; s += v; q += v*v; }
  float key  = hc[b*HC + m];
  float kstr = expf(hc[b*HC + 64]);
  float gate = sigmoidf(hc[b*HC + 65]);
  float nk = fmaxf(fabsf(key)*8.0f, EPSF);
  float nm = fmaxf(sqrtf(q), EPSF);
  float z  = kstr * (key*s) / (nk*nm);
  __shared__ float sm[2], ss[2];
  float mx = wave_max(z);
  if ((m & 63) == 0) sm[m>>6] = mx;
  __syncthreads();
  mx = fmaxf(sm[0], sm[1]);
  float e = expf(z - mx);
  float w = wave_sum(e);
  if ((m & 63) == 0) ss[m>>6] = w;
  __syncthreads();
  float content = e / (ss[0] + ss[1]);
  wout[b*MM + m] = gate*content + (1.0f - gate)*heads0[m];   // heads[0]: batch-0 row broadcast
}

// ---------------- read_in -> xcat3[:,512:576] ----------------
__global__ void k_readin(const float* __restrict__ rw, const float* __restrict__ mem,
                         float* __restrict__ xcat3){
  int b = blockIdx.x, d = threadIdx.x;    // 64 threads
  float s = 0.f;
  for (int m = 0; m < MM; m++) s += rw[b*MM + m] * mem[((long)b*MM + m)*DD + d];
  xcat3[b*576 + 512 + d] = s;
}

// ---------------- new_memory ----------------
__global__ void k_newmem(const float* __restrict__ mem, const float* __restrict__ ww,
                         const float* __restrict__ wh, float* __restrict__ out){
  int idx = blockIdx.x*256 + threadIdx.x;    // 524288
  if (idx >= BB*MM*DD) return;
  int b = idx >> 13;
  int m = (idx & 8191) >> 6;
  float w0 = ww[b*MM + m];
  float we = sigmoidf(wh[b*HC + 68 + m]);
  float wa = sigmoidf(wh[b*HC + 132 + m]);
  out[idx] = mem[idx]*(1.0f - w0*we) + w0*wa;
}

// ---------------- main LSTM fused: wave per (b,j) computes 4 gate dots + elementwise ----
// grid (128 j-quads, 64 b), 256 threads (4 waves). Also emits c1 as bf16 (c1b).
__global__ __launch_bounds__(256) void k_lstm_main(const float* __restrict__ xcat3,
                                                   const float* __restrict__ h0,
                                                   const float* __restrict__ lWih,
                                                   const float* __restrict__ lWhh,
                                                   const float* __restrict__ bih,
                                                   const float* __restrict__ bhh,
                                                   const float* __restrict__ c0,
                                                   float* __restrict__ h1,
                                                   float* __restrict__ c1,
                                                   unsigned short* __restrict__ c1b){
  int wid = threadIdx.x >> 6, lane = threadIdx.x & 63;
  int j = blockIdx.x*4 + wid;        // 0..511
  int b = blockIdx.y;
  const float4* A1 = (const float4*)(xcat3 + (long)b*576);   // 144 f4
  const float4* A2 = (const float4*)(h0 + (long)b*HH);       // 128 f4
  float gv[4];
  #pragma unroll
  for (int g = 0; g < 4; g++){
    int n = g*HH + j;
    const float4* W1 = (const float4*)(lWih + (long)n*576);
    const float4* W2 = (const float4*)(lWhh + (long)n*HH);
    float s = 0.f;
    #pragma unroll
    for (int i = 0; i < 3; i++){
      int k = lane + i*64;
      if (k < 144){ float4 a = A1[k], w = W1[k]; s += a.x*w.x + a.y*w.y + a.z*w.z + a.w*w.w; }
    }
    #pragma unroll
    for (int i = 0; i < 2; i++){
      int k = lane + i*64;
      float4 a = A2[k], w = W2[k]; s += a.x*w.x + a.y*w.y + a.z*w.z + a.w*w.w;
    }
    gv[g] = wave_sum(s);
  }
  if (lane == 0){
    #pragma unroll
    for (int g = 0; g < 4; g++){ int n = g*HH + j; gv[g] += bih[n] + bhh[n]; }
    float c2 = sigmoidf(gv[1])*c0[b*HH + j] + sigmoidf(gv[0])*tanhf(gv[2]);
    h1[b*HH + j] = sigmoidf(gv[3])*tanhf(c2);
    c1[b*HH + j] = c2;
    c1b[b*HH + j] = bf16_rne(c2);
  }
}

// ---------------- logits: bf16 MFMA, no LDS. ------------------------------------------
// C(64,50000) = c1b(64,512,bf16) @ out_W^T(fp32->bf16 on the fly) + bias
// m-split across the 4 waves of a block: wave w computes the 16 output rows [16w,16w+16)
// for one 16-wide n-strip. grid = 3125 blocks (50000/16 strips, exact — no guards).
// K=512 processed in 2 register-buffered chunks (16 W float4 + 8 A bf16x8 in flight per
// wave) to maximize outstanding-load depth; 12500 waves total for latency hiding.
__global__ __launch_bounds__(256, 4) void k_logits_mfma(const unsigned short* __restrict__ Ab,
                                                        const float* __restrict__ W,
                                                        const float* __restrict__ bias,
                                                        float* __restrict__ C){
  int mb = threadIdx.x >> 6, lane = threadIdx.x & 63;   // mb: m-block 0..3
  int strip = blockIdx.x;                               // 0..3124
  int nl = lane & 15;                                   // n within strip / A-row within m-block
  int q  = lane >> 4;                                   // k sub-chunk
  int n  = strip*16 + nl;
  const float4*  W4 = (const float4*)(W + (long)n*HH + q*8);            // +8 f4 per ks
  const bf16x8*  Ap = (const bf16x8*)(Ab + (long)(mb*16 + nl)*HH + q*8); // +4 per ks
  f32x4 acc = {0.f,0.f,0.f,0.f};
  #pragma unroll
  for (int c = 0; c < 2; c++){
    float4 wv[16];
    bf16x8 av[8];
    #pragma unroll
    for (int i = 0; i < 8; i++){
      int ks = c*8 + i;
      wv[2*i]   = W4[ks*8];
      wv[2*i+1] = W4[ks*8 + 1];
      av[i]     = Ap[ks*4];
    }
    #pragma unroll
    for (int i = 0; i < 8; i++){
      float4 w0 = wv[2*i], w1 = wv[2*i+1];
      bf16x8 bf;
      bf[0] = (short)bf16_rne(w0.x); bf[1] = (short)bf16_rne(w0.y);
      bf[2] = (short)bf16_rne(w0.z); bf[3] = (short)bf16_rne(w0.w);
      bf[4] = (short)bf16_rne(w1.x); bf[5] = (short)bf16_rne(w1.y);
      bf[6] = (short)bf16_rne(w1.z); bf[7] = (short)bf16_rne(w1.w);
      acc = __builtin_amdgcn_mfma_f32_16x16x32_bf16(av[i], bf, acc, 0, 0, 0);
    }
  }
  float bv = bias[n];
  #pragma unroll
  for (int r = 0; r < 4; r++){
    int m = mb*16 + q*4 + r;
    C[(long)m*VV + n] = acc[r] + bv;
  }
}

// ---------------- 3-stage log_softmax over V ----------------
__global__ __launch_bounds__(256) void k_ls1(const float* __restrict__ lp,
                                             float* __restrict__ pm, float* __restrict__ ps){
  int b = blockIdx.y, c = blockIdx.x, t = threadIdx.x;   // grid (25, 64)
  const float* row = lp + (long)b*VV + c*2000;
  float mx = -INFINITY;
  for (int i = t; i < 2000; i += 256) mx = fmaxf(mx, row[i]);
  __shared__ float sm[4], ss[4];
  mx = wave_max(mx);
  if ((t & 63) == 0) sm[t>>6] = mx;
  __syncthreads();
  mx = fmaxf(fmaxf(sm[0], sm[1]), fmaxf(sm[2], sm[3]));
  float s = 0.f;
  for (int i = t; i < 2000; i += 256) s += expf(row[i] - mx);
  s = wave_sum(s);
  if ((t & 63) == 0) ss[t>>6] = s;
  __syncthreads();
  if (t == 0){ pm[b*25 + c] = mx; ps[b*25 + c] = ss[0]+ss[1]+ss[2]+ss[3]; }
}

__global__ void k_ls2(const float* __restrict__ pm, const float* __restrict__ ps,
                      float* __restrict__ lse){
  int b = threadIdx.x;    // 64
  float m = -INFINITY;
  for (int c = 0; c < 25; c++) m = fmaxf(m, pm[b*25 + c]);
  float s = 0.f;
  for (int c = 0; c < 25; c++) s += ps[b*25 + c]*expf(pm[b*25 + c] - m);
  lse[b] = m + logf(s);
}

__global__ void k_ls3(float* __restrict__ lp, const float* __restrict__ lse){
  int idx = blockIdx.x*256 + threadIdx.x;
  if (idx >= BB*VV) return;
  int b = idx / VV;
  lp[idx] -= lse[b];
}

extern "C" void kernel_launch(void* const* d_in, const int* in_sizes, int n_in,
                              void* d_out, int out_size, void* d_ws, size_t ws_size,
                              hipStream_t stream) {
  const int*   ids     = (const int*)  d_in[0];
  const float* h0      = (const float*)d_in[1];
  const float* c0      = (const float*)d_in[2];
  const float* enc     = (const float*)d_in[3];
  const float* cov     = (const float*)d_in[5];
  const float* mem     = (const float*)d_in[6];
  const float* rheads  = (const float*)d_in[7];
  const float* wheads  = (const float*)d_in[8];
  const float* read_h  = (const float*)d_in[9];
  const float* read_c  = (const float*)d_in[10];
  const float* write_h = (const float*)d_in[11];
  const float* write_c = (const float*)d_in[12];
  const float* emb     = (const float*)d_in[13];
  const float* attn_W  = (const float*)d_in[14];
  const float* attn_b  = (const float*)d_in[15];
  const float* cov_W   = (const float*)d_in[16];
  const float* state_W = (const float*)d_in[17];
  const float* comb_W  = (const float*)d_in[18];
  const float* comb_b  = (const float*)d_in[19];
  const float* rpre_W  = (const float*)d_in[20];
  const float* rpre_b  = (const float*)d_in[21];
  const float* wpre_W  = (const float*)d_in[22];
  const float* wpre_b  = (const float*)d_in[23];
  const float* r_Wih   = (const float*)d_in[24];
  const float* r_Whh   = (const float*)d_in[25];
  const float* r_bih   = (const float*)d_in[26];
  const float* r_bhh   = (const float*)d_in[27];
  const float* w_Wih   = (const float*)d_in[28];
  const float* w_Whh   = (const float*)d_in[29];
  const float* w_bih   = (const float*)d_in[30];
  const float* w_bhh   = (const float*)d_in[31];
  const float* l_Wih   = (const float*)d_in[32];
  const float* l_Whh   = (const float*)d_in[33];
  const float* l_bih   = (const float*)d_in[34];
  const float* l_bhh   = (const float*)d_in[35];
  const float* out_W   = (const float*)d_in[36];
  const float* out_b   = (const float*)d_in[37];

  float* out  = (float*)d_out;
  float* lp   = out;                 // (64, 50000)
  float* h1   = out + 3200000;       // (64, 512)
  float* c1   = h1 + 32768;          // (64, 512)
  float* nmem = c1 + 32768;          // (64, 128, 64)
  float* ncov = nmem + 524288;       // (64, 400)

  float* w = (float*)d_ws;
  float* xcat1 = w;                  // 65536   [embedded | h0]
  float* xcat2 = xcat1 + 65536;      // 65536   [embedded | attn_applied]
  float* xcat3 = xcat2 + 65536;      // 36864   [out0 | read_in]
  float* ia    = xcat3 + 36864;      // 25600
  float* ts    = ia + 25600;         // 25600
  float* tc    = ts + 25600;         // 25600
  float* aw    = tc + 25600;         // 25600
  float* U     = aw + 25600;         // 557056  shared: attn partials(524288) / pre partials(65536)
  float* pre_r = U + 557056;         // 4096
  float* pre_w = pre_r + 4096;       // 4096
  float* g_r   = pre_w + 4096;       // 66560
  float* g_w   = g_r + 66560;        // 66560
  float* rh    = g_w + 66560;        // 16640
  float* wh    = rh + 16640;         // 16640
  float* rw    = wh + 16640;         // 8192
  float* wwgt  = rw + 8192;          // 8192
  float* pm    = wwgt + 8192;        // 1600
  float* ps    = pm + 1600;          // 1600
  float* lse   = ps + 1600;          // 64
  unsigned short* c1b = (unsigned short*)(lse + 64);   // 32768 bf16 (16384 floats)

  // attention path
  k_embed<<<128, 256, 0, stream>>>(ids, emb, h0, xcat1, xcat2);
  k_gemv<1,0><<<dim3(100,64), 256, 0, stream>>>(xcat1, xcat1, attn_W, attn_b, ia, 1024, LL, LL);
  k_gemv<0,0><<<dim3(100,64), 256, 0, stream>>>(c0, c0, state_W, nullptr, ts, HH, LL, LL);
  k_cov<<<100, 256, 0, stream>>>(cov, ia, ncov);
  k_gemv<0,1><<<dim3(100,64), 256, 0, stream>>>(cov, ia, cov_W, nullptr, tc, LL, LL, LL);
  k_softmax_aw<<<64, 256, 0, stream>>>(ia, ts, tc, aw);
  k_attn_part<<<dim3(64,16), 256, 0, stream>>>(aw, enc, U);
  k_attn_reduce<<<128, 256, 0, stream>>>(U, xcat2);
  k_gemv<1,0><<<dim3(128,64), 256, 0, stream>>>(xcat2, xcat2, comb_W, comb_b, xcat3, 1024, HH, 576);

  // pre-projections (K=8704, 8-way K-split GEMV)
  k_pre_gemv<<<dim3(16,64,16), 256, 0, stream>>>(h0, mem, rpre_W, wpre_W, U);
  k_pre_reduce<<<32, 256, 0, stream>>>(U, rpre_b, wpre_b, pre_r, pre_w);

  // read/write head gates + LSTMs (fused)
  k_gates_rw<<<dim3(260,64,2), 256, 0, stream>>>(pre_r, pre_w, read_h, write_h,
      r_Wih, r_Whh, r_bih, r_bhh, w_Wih, w_Whh, w_bih, w_bhh, g_r, g_w);
  k_lstm_rw<<<130, 256, 0, stream>>>(g_r, g_w, read_c, write_c, rh, wh);

  // addressing + memory ops
  k_address<<<dim3(64,2), 128, 0, stream>>>(rh, wh, rheads, wheads, mem, rw, wwgt);
  k_readin<<<64, 64, 0, stream>>>(rw, mem, xcat3);
  k_newmem<<<2048, 256, 0, stream>>>(mem, wwgt, wh, nmem);

  // main LSTM (fused gates GEMV + elementwise, emits bf16 c1)
  k_lstm_main<<<dim3(128,64), 256, 0, stream>>>(xcat3, h0, l_Wih, l_Whh, l_bih, l_bhh,
                                                c0, h1, c1, c1b);

  // output projection (bf16 MFMA, m-split across waves) + log_softmax
  k_logits_mfma<<<3125, 256, 0, stream>>>(c1b, out_W, out_b, lp);
  k_ls1<<<dim3(25,64), 256, 0, stream>>>(lp, pm, ps);
  k_ls2<<<1, 64, 0, stream>>>(pm, ps, lse);
  k_ls3<<<12500, 256, 0, stream>>>(lp, lse);
}

// Round 2
// 512.325 us; speedup vs baseline: 1.0179x; 1.0179x over previous
//
#include <hip/hip_runtime.h>
#include <math.h>

#define BB 64
#define HH 512
#define VV 50000
#define LL 400
#define MM 128
#define DD 64
#define HC 260
#define EPSF 1e-8f

typedef __attribute__((ext_vector_type(8))) short bf16x8;
typedef __attribute__((ext_vector_type(4))) float f32x4;

__device__ __forceinline__ float sigmoidf(float x){ return 1.0f/(1.0f+expf(-x)); }
__device__ __forceinline__ unsigned short bf16_rne(float f){
  unsigned u = __float_as_uint(f);
  return (unsigned short)((u + 0x7fffu + ((u >> 16) & 1u)) >> 16);
}
__device__ __forceinline__ float wave_max(float v){
  #pragma unroll
  for(int o=32;o;o>>=1) v = fmaxf(v, __shfl_xor(v,o));
  return v;
}
__device__ __forceinline__ float wave_sum(float v){
  #pragma unroll
  for(int o=32;o;o>>=1) v += __shfl_xor(v,o);
  return v;
}

// ---------------- embed + concat builders ----------------
__global__ void k_embed(const int* __restrict__ ids, const float* __restrict__ emb,
                        const float* __restrict__ h0, float* __restrict__ xcat1,
                        float* __restrict__ xcat2){
  int idx = blockIdx.x*256 + threadIdx.x;           // 64*512
  if (idx >= BB*HH) return;
  int b = idx >> 9, h = idx & 511;
  float e = emb[(long)ids[b]*HH + h];
  xcat1[b*1024 + h] = e;
  xcat2[b*1024 + h] = e;
  xcat1[b*1024 + 512 + h] = h0[idx];
}

// ---------------- wave-per-output GEMV: C[b,n] = (A[+A2])[b,:] . W[n,:] ----------------
template<int NB, int FUSE>
__global__ __launch_bounds__(256) void k_gemv(const float* __restrict__ A,
                                              const float* __restrict__ A2,
                                              const float* __restrict__ W,
                                              const float* __restrict__ b1,
                                              float* __restrict__ C,
                                              int K, int N, int ldc){
  int b = blockIdx.y;
  int wid = threadIdx.x >> 6, lane = threadIdx.x & 63;
  int n = blockIdx.x*4 + wid;
  if (n >= N) return;
  const float4* A4  = (const float4*)(A + (long)b*K);
  const float4* A24 = (const float4*)(A2 + (long)b*K);
  const float4* W4  = (const float4*)(W + (long)n*K);
  int K4 = K >> 2;
  float acc = 0.f;
  for (int k = lane; k < K4; k += 64){
    float4 a = A4[k];
    if (FUSE){ float4 a2 = A24[k]; a.x+=a2.x; a.y+=a2.y; a.z+=a2.z; a.w+=a2.w; }
    float4 w = W4[k];
    acc += a.x*w.x + a.y*w.y + a.z*w.z + a.w*w.w;
  }
  acc = wave_sum(acc);
  if (lane == 0){
    if (NB) acc += b1[n];
    C[(long)b*ldc + n] = acc;
  }
}

// ---------------- new_coverage = coverage + ia ----------------
__global__ void k_cov(const float* __restrict__ cov, const float* __restrict__ ia,
                      float* __restrict__ out){
  int idx = blockIdx.x*256 + threadIdx.x;     // 25600
  if (idx >= BB*LL) return;
  out[idx] = cov[idx] + ia[idx];
}

// ---------------- aw = softmax(tc+ia+ts) over L ----------------
__global__ __launch_bounds__(256) void k_softmax_aw(const float* __restrict__ ia,
                                                    const float* __restrict__ ts,
                                                    const float* __restrict__ tc,
                                                    float* __restrict__ aw){
  int b = blockIdx.x, t = threadIdx.x;
  int i0 = t, i1 = t + 256;
  float x0 = ia[b*LL+i0] + ts[b*LL+i0] + tc[b*LL+i0];
  float x1 = (i1 < LL) ? (ia[b*LL+i1] + ts[b*LL+i1] + tc[b*LL+i1]) : -INFINITY;
  __shared__ float sm[4], ss[4];
  float m = wave_max(fmaxf(x0, x1));
  if ((t & 63) == 0) sm[t>>6] = m;
  __syncthreads();
  m = fmaxf(fmaxf(sm[0], sm[1]), fmaxf(sm[2], sm[3]));
  float e0 = expf(x0 - m);
  float e1 = (i1 < LL) ? expf(x1 - m) : 0.0f;
  float s = wave_sum(e0 + e1);
  if ((t & 63) == 0) ss[t>>6] = s;
  __syncthreads();
  float tot = ss[0] + ss[1] + ss[2] + ss[3];
  float inv = 1.0f / tot;
  aw[b*LL + i0] = e0 * inv;
  if (i1 < LL) aw[b*LL + i1] = e1 * inv;
}

// ---------------- attn_applied partials: grid (64 b, 16 l-chunks of 25) ----------------
__global__ __launch_bounds__(256) void k_attn_part(const float* __restrict__ aw,
                                                   const float* __restrict__ enc,
                                                   float* __restrict__ part){
  int b = blockIdx.x, lc = blockIdx.y, t = threadIdx.x;
  const float* awb = aw + b*LL + lc*25;
  const float* eb  = enc + ((long)b*LL + lc*25)*HH;
  float a0 = 0.f, a1 = 0.f;
  for (int l = 0; l < 25; l++){
    float a = awb[l];
    a0 += a * eb[(long)l*HH + t];
    a1 += a * eb[(long)l*HH + t + 256];
  }
  part[((b*16 + lc) << 9) + t]       = a0;
  part[((b*16 + lc) << 9) + t + 256] = a1;
}

__global__ void k_attn_reduce(const float* __restrict__ part, float* __restrict__ xcat2){
  int idx = blockIdx.x*256 + threadIdx.x;       // 64*512
  if (idx >= BB*HH) return;
  int b = idx >> 9, h = idx & 511;
  float s = 0.f;
  #pragma unroll
  for (int lc = 0; lc < 16; lc++) s += part[((b*16 + lc) << 9) + h];
  xcat2[b*1024 + 512 + h] = s;
}

// ---------------- pre GEMV, K-split: grid (16 n-quads, 64 b, which*8+chunk) ----------------
// pre = [h0 | mem] @ {r,w}pre_W^T ; K=8704 split into 8 chunks of 1088.
__global__ __launch_bounds__(256) void k_pre_gemv(const float* __restrict__ h0,
                                                  const float* __restrict__ mem,
                                                  const float* __restrict__ rW,
                                                  const float* __restrict__ wW,
                                                  float* __restrict__ part){
  int wid = threadIdx.x >> 6, lane = threadIdx.x & 63;
  int n = blockIdx.x*4 + wid;        // 0..63
  int b = blockIdx.y;
  int z = blockIdx.z;                // which*8 + chunk
  int which = z >> 3, chunk = z & 7;
  const float* W = which ? wW : rW;
  const float4* W4 = (const float4*)(W + (long)n*8704 + chunk*1088);
  const float4* H4 = (const float4*)(h0 + (long)b*HH);
  const float4* M4 = (const float4*)(mem + (long)b*8192 + (chunk*1088 - 512));
  float acc = 0.f;
  #pragma unroll
  for (int i = 0; i < 5; i++){
    int k4 = lane + i*64;            // float4 index within chunk (272 total)
    if (k4 < 272){
      int kg4 = chunk*272 + k4;      // global float4 index
      float4 a = (kg4 < 128) ? H4[kg4] : M4[k4];
      float4 w = W4[k4];
      acc += a.x*w.x + a.y*w.y + a.z*w.z + a.w*w.w;
    }
  }
  acc = wave_sum(acc);
  if (lane == 0) part[z*4096 + b*64 + n] = acc;
}

__global__ void k_pre_reduce(const float* __restrict__ part, const float* __restrict__ rb,
                             const float* __restrict__ wb, float* __restrict__ pre_r,
                             float* __restrict__ pre_w){
  int idx = blockIdx.x*256 + threadIdx.x;     // 8192
  if (idx >= 8192) return;
  int which = idx >> 12;
  int r = idx & 4095;
  float s = 0.f;
  #pragma unroll
  for (int c = 0; c < 8; c++) s += part[((which<<3)+c)*4096 + r];
  int n = r & 63;
  s += which ? wb[n] : rb[n];
  (which ? pre_w : pre_r)[r] = s;
}

// ---------------- fused gates GEMV for r/w heads: grid (260, 64, 2) ----------------
__global__ __launch_bounds__(256) void k_gates_rw(const float* __restrict__ pre_r,
    const float* __restrict__ pre_w, const float* __restrict__ read_h,
    const float* __restrict__ write_h,
    const float* __restrict__ rWih, const float* __restrict__ rWhh,
    const float* __restrict__ rbih, const float* __restrict__ rbhh,
    const float* __restrict__ wWih, const float* __restrict__ wWhh,
    const float* __restrict__ wbih, const float* __restrict__ wbhh,
    float* __restrict__ g_r, float* __restrict__ g_w){
  int which = blockIdx.z;
  int b = blockIdx.y;
  int wid = threadIdx.x >> 6, lane = threadIdx.x & 63;
  int n = blockIdx.x*4 + wid;     // < 1040
  const float* pre = which ? pre_w : pre_r;     // (64,64)
  const float* hh  = which ? write_h : read_h;  // (64,260)
  const float* Wih = which ? wWih : rWih;       // (1040,64)
  const float* Whh = which ? wWhh : rWhh;       // (1040,260)
  float acc = pre[b*64 + lane] * Wih[n*64 + lane];
  const float* hb = hh + b*HC;
  const float* wr = Whh + (long)n*HC;
  #pragma unroll
  for (int i = 0; i < 5; i++){
    int k = lane + i*64;
    if (k < HC) acc += hb[k]*wr[k];
  }
  acc = wave_sum(acc);
  if (lane == 0){
    acc += (which ? wbih : rbih)[n] + (which ? wbhh : rbhh)[n];
    (which ? g_w : g_r)[(long)b*4*HC + n] = acc;
  }
}

// ---------------- fused r+w LSTM elementwise ----------------
__global__ void k_lstm_rw(const float* __restrict__ g_r, const float* __restrict__ g_w,
                          const float* __restrict__ read_c, const float* __restrict__ write_c,
                          float* __restrict__ rh, float* __restrict__ wh){
  int idx = blockIdx.x*256 + threadIdx.x;    // 2*64*260 = 33280
  if (idx >= 2*BB*HC) return;
  int which = idx >= BB*HC;
  int r = which ? idx - BB*HC : idx;
  int b = r / HC, j = r - b*HC;
  const float* g = (which ? g_w : g_r) + (long)b*4*HC;
  float c2 = sigmoidf(g[HC + j]) * (which ? write_c : read_c)[r]
           + sigmoidf(g[j]) * tanhf(g[2*HC + j]);
  (which ? wh : rh)[r] = sigmoidf(g[3*HC + j]) * tanhf(c2);
}

// ---------------- addressing: grid (64, 2), 128 threads ----------------
__global__ __launch_bounds__(128) void k_address(const float* __restrict__ rh,
                                                 const float* __restrict__ whv,
                                                 const float* __restrict__ rheads,
                                                 const float* __restrict__ wheads,
                                                 const float* __restrict__ mem,
                                                 float* __restrict__ rwout,
                                                 float* __restrict__ wwout){
  int which = blockIdx.y;
  int b = blockIdx.x, m = threadIdx.x;
  const float* hc = which ? whv : rh;
  const float* heads0 = which ? wheads : rheads;
  float* wout = which ? wwout : rwout;
  const float* mr = mem + ((long)b*MM + m)*DD;
  float s = 0.f, q = 0.f;
  #pragma unroll 8
  for (int d = 0; d < DD; d++){ float v = mr[d]; s += v; q += v*v; }
  float key  = hc[b*HC + m];
  float kstr = expf(hc[b*HC + 64]);
  float gate = sigmoidf(hc[b*HC + 65]);
  float nk = fmaxf(fabsf(key)*8.0f, EPSF);
  float nm = fmaxf(sqrtf(q), EPSF);
  float z  = kstr * (key*s) / (nk*nm);
  __shared__ float sm[2], ss[2];
  float mx = wave_max(z);
  if ((m & 63) == 0) sm[m>>6] = mx;
  __syncthreads();
  mx = fmaxf(sm[0], sm[1]);
  float e = expf(z - mx);
  float w = wave_sum(e);
  if ((m & 63) == 0) ss[m>>6] = w;
  __syncthreads();
  float content = e / (ss[0] + ss[1]);
  wout[b*MM + m] = gate*content + (1.0f - gate)*heads0[m];   // heads[0]: batch-0 row broadcast
}

// ---------------- read_in -> xcat3[:,512:576] ----------------
__global__ void k_readin(const float* __restrict__ rw, const float* __restrict__ mem,
                         float* __restrict__ xcat3){
  int b = blockIdx.x, d = threadIdx.x;    // 64 threads
  float s = 0.f;
  for (int m = 0; m < MM; m++) s += rw[b*MM + m] * mem[((long)b*MM + m)*DD + d];
  xcat3[b*576 + 512 + d] = s;
}

// ---------------- new_memory ----------------
__global__ void k_newmem(const float* __restrict__ mem, const float* __restrict__ ww,
                         const float* __restrict__ wh, float* __restrict__ out){
  int idx = blockIdx.x*256 + threadIdx.x;    // 524288
  if (idx >= BB*MM*DD) return;
  int b = idx >> 13;
  int m = (idx & 8191) >> 6;
  float w0 = ww[b*MM + m];
  float we = sigmoidf(wh[b*HC + 68 + m]);
  float wa = sigmoidf(wh[b*HC + 132 + m]);
  out[idx] = mem[idx]*(1.0f - w0*we) + w0*wa;
}

// ---------------- main LSTM fused: wave per (b,j) computes 4 gate dots + elementwise ----
// grid (128 j-quads, 64 b), 256 threads (4 waves). Also emits c1 as bf16 (c1b).
__global__ __launch_bounds__(256) void k_lstm_main(const float* __restrict__ xcat3,
                                                   const float* __restrict__ h0,
                                                   const float* __restrict__ lWih,
                                                   const float* __restrict__ lWhh,
                                                   const float* __restrict__ bih,
                                                   const float* __restrict__ bhh,
                                                   const float* __restrict__ c0,
                                                   float* __restrict__ h1,
                                                   float* __restrict__ c1,
                                                   unsigned short* __restrict__ c1b){
  int wid = threadIdx.x >> 6, lane = threadIdx.x & 63;
  int j = blockIdx.x*4 + wid;        // 0..511
  int b = blockIdx.y;
  const float4* A1 = (const float4*)(xcat3 + (long)b*576);   // 144 f4
  const float4* A2 = (const float4*)(h0 + (long)b*HH);       // 128 f4
  float gv[4];
  #pragma unroll
  for (int g = 0; g < 4; g++){
    int n = g*HH + j;
    const float4* W1 = (const float4*)(lWih + (long)n*576);
    const float4* W2 = (const float4*)(lWhh + (long)n*HH);
    float s = 0.f;
    #pragma unroll
    for (int i = 0; i < 3; i++){
      int k = lane + i*64;
      if (k < 144){ float4 a = A1[k], w = W1[k]; s += a.x*w.x + a.y*w.y + a.z*w.z + a.w*w.w; }
    }
    #pragma unroll
    for (int i = 0; i < 2; i++){
      int k = lane + i*64;
      float4 a = A2[k], w = W2[k]; s += a.x*w.x + a.y*w.y + a.z*w.z + a.w*w.w;
    }
    gv[g] = wave_sum(s);
  }
  if (lane == 0){
    #pragma unroll
    for (int g = 0; g < 4; g++){ int n = g*HH + j; gv[g] += bih[n] + bhh[n]; }
    float c2 = sigmoidf(gv[1])*c0[b*HH + j] + sigmoidf(gv[0])*tanhf(gv[2]);
    h1[b*HH + j] = sigmoidf(gv[3])*tanhf(c2);
    c1[b*HH + j] = c2;
    c1b[b*HH + j] = bf16_rne(c2);
  }
}

// ---------------- logits: bf16 MFMA, no LDS. ------------------------------------------
// C(64,50000) = c1b(64,512,bf16) @ out_W^T(fp32->bf16 on the fly) + bias
// Mapping (round-0, 62us): wave = one 16-n strip x all 64 m rows. 782 blocks x 4 waves.
// Latency fix: issue ALL 32 W float4 loads (full K=512 row segment, 512 B/lane in
// flight) up-front, fenced with sched_barrier(0) so the scheduler cannot sink them
// into the compute. Per-ks sched_barrier keeps the 64 A loads (L1/L2-resident c1b)
// from being hoisted into one register-blowing batch. W drains via incremental
// vmcnt waits overlapped with convert+MFMA.
__global__ __launch_bounds__(256, 2) void k_logits_mfma(const unsigned short* __restrict__ Ab,
                                                        const float* __restrict__ W,
                                                        const float* __restrict__ bias,
                                                        float* __restrict__ C){
  int wid = threadIdx.x >> 6, lane = threadIdx.x & 63;
  int strip = blockIdx.x*4 + wid;          // 3125 strips of 16 n
  if (strip >= 3125) return;
  int nl = lane & 15;                      // n offset within strip / m offset in frags
  int q  = lane >> 4;                      // quad -> k = q*8 + ks*32
  int n  = strip*16 + nl;
  const float4* W4 = (const float4*)(W + (long)n*HH);        // 128 f4 per row

  // ---- issue the entire W batch (32 x 16B per lane) ----
  float4 wv[32];
  #pragma unroll
  for (int ks = 0; ks < 16; ks++){
    wv[2*ks]   = W4[ks*8 + q*2];
    wv[2*ks+1] = W4[ks*8 + q*2 + 1];
  }
  __builtin_amdgcn_sched_barrier(0);

  const bf16x8* A0 = (const bf16x8*)Ab + (long)(0*16 + nl)*64 + q;
  const bf16x8* A1 = (const bf16x8*)Ab + (long)(1*16 + nl)*64 + q;
  const bf16x8* A2 = (const bf16x8*)Ab + (long)(2*16 + nl)*64 + q;
  const bf16x8* A3 = (const bf16x8*)Ab + (long)(3*16 + nl)*64 + q;
  f32x4 acc0 = {0.f,0.f,0.f,0.f}, acc1 = acc0, acc2 = acc0, acc3 = acc0;
  #pragma unroll
  for (int ks = 0; ks < 16; ks++){
    float4 w0 = wv[2*ks], w1 = wv[2*ks+1];
    bf16x8 bf;
    bf[0] = (short)bf16_rne(w0.x); bf[1] = (short)bf16_rne(w0.y);
    bf[2] = (short)bf16_rne(w0.z); bf[3] = (short)bf16_rne(w0.w);
    bf[4] = (short)bf16_rne(w1.x); bf[5] = (short)bf16_rne(w1.y);
    bf[6] = (short)bf16_rne(w1.z); bf[7] = (short)bf16_rne(w1.w);
    bf16x8 a0 = A0[ks*4];
    bf16x8 a1 = A1[ks*4];
    bf16x8 a2 = A2[ks*4];
    bf16x8 a3 = A3[ks*4];
    acc0 = __builtin_amdgcn_mfma_f32_16x16x32_bf16(a0, bf, acc0, 0, 0, 0);
    acc1 = __builtin_amdgcn_mfma_f32_16x16x32_bf16(a1, bf, acc1, 0, 0, 0);
    acc2 = __builtin_amdgcn_mfma_f32_16x16x32_bf16(a2, bf, acc2, 0, 0, 0);
    acc3 = __builtin_amdgcn_mfma_f32_16x16x32_bf16(a3, bf, acc3, 0, 0, 0);
    __builtin_amdgcn_sched_barrier(0);
  }
  float bv = bias[n];
  #pragma unroll
  for (int r = 0; r < 4; r++){
    int m = q*4 + r;
    C[(long)(m     )*VV + n] = acc0[r] + bv;
    C[(long)(m + 16)*VV + n] = acc1[r] + bv;
    C[(long)(m + 32)*VV + n] = acc2[r] + bv;
    C[(long)(m + 48)*VV + n] = acc3[r] + bv;
  }
}

// ---------------- 3-stage log_softmax over V ----------------
__global__ __launch_bounds__(256) void k_ls1(const float* __restrict__ lp,
                                             float* __restrict__ pm, float* __restrict__ ps){
  int b = blockIdx.y, c = blockIdx.x, t = threadIdx.x;   // grid (25, 64)
  const float* row = lp + (long)b*VV + c*2000;
  float mx = -INFINITY;
  for (int i = t; i < 2000; i += 256) mx = fmaxf(mx, row[i]);
  __shared__ float sm[4], ss[4];
  mx = wave_max(mx);
  if ((t & 63) == 0) sm[t>>6] = mx;
  __syncthreads();
  mx = fmaxf(fmaxf(sm[0], sm[1]), fmaxf(sm[2], sm[3]));
  float s = 0.f;
  for (int i = t; i < 2000; i += 256) s += expf(row[i] - mx);
  s = wave_sum(s);
  if ((t & 63) == 0) ss[t>>6] = s;
  __syncthreads();
  if (t == 0){ pm[b*25 + c] = mx; ps[b*25 + c] = ss[0]+ss[1]+ss[2]+ss[3]; }
}

__global__ void k_ls2(const float* __restrict__ pm, const float* __restrict__ ps,
                      float* __restrict__ lse){
  int b = threadIdx.x;    // 64
  float m = -INFINITY;
  for (int c = 0; c < 25; c++) m = fmaxf(m, pm[b*25 + c]);
  float s = 0.f;
  for (int c = 0; c < 25; c++) s += ps[b*25 + c]*expf(pm[b*25 + c] - m);
  lse[b] = m + logf(s);
}

__global__ void k_ls3(float* __restrict__ lp, const float* __restrict__ lse){
  int idx = blockIdx.x*256 + threadIdx.x;
  if (idx >= BB*VV) return;
  int b = idx / VV;
  lp[idx] -= lse[b];
}

extern "C" void kernel_launch(void* const* d_in, const int* in_sizes, int n_in,
                              void* d_out, int out_size, void* d_ws, size_t ws_size,
                              hipStream_t stream) {
  const int*   ids     = (const int*)  d_in[0];
  const float* h0      = (const float*)d_in[1];
  const float* c0      = (const float*)d_in[2];
  const float* enc     = (const float*)d_in[3];
  const float* cov     = (const float*)d_in[5];
  const float* mem     = (const float*)d_in[6];
  const float* rheads  = (const float*)d_in[7];
  const float* wheads  = (const float*)d_in[8];
  const float* read_h  = (const float*)d_in[9];
  const float* read_c  = (const float*)d_in[10];
  const float* write_h = (const float*)d_in[11];
  const float* write_c = (const float*)d_in[12];
  const float* emb     = (const float*)d_in[13];
  const float* attn_W  = (const float*)d_in[14];
  const float* attn_b  = (const float*)d_in[15];
  const float* cov_W   = (const float*)d_in[16];
  const float* state_W = (const float*)d_in[17];
  const float* comb_W  = (const float*)d_in[18];
  const float* comb_b  = (const float*)d_in[19];
  const float* rpre_W  = (const float*)d_in[20];
  const float* rpre_b  = (const float*)d_in[21];
  const float* wpre_W  = (const float*)d_in[22];
  const float* wpre_b  = (const float*)d_in[23];
  const float* r_Wih   = (const float*)d_in[24];
  const float* r_Whh   = (const float*)d_in[25];
  const float* r_bih   = (const float*)d_in[26];
  const float* r_bhh   = (const float*)d_in[27];
  const float* w_Wih   = (const float*)d_in[28];
  const float* w_Whh   = (const float*)d_in[29];
  const float* w_bih   = (const float*)d_in[30];
  const float* w_bhh   = (const float*)d_in[31];
  const float* l_Wih   = (const float*)d_in[32];
  const float* l_Whh   = (const float*)d_in[33];
  const float* l_bih   = (const float*)d_in[34];
  const float* l_bhh   = (const float*)d_in[35];
  const float* out_W   = (const float*)d_in[36];
  const float* out_b   = (const float*)d_in[37];

  float* out  = (float*)d_out;
  float* lp   = out;                 // (64, 50000)
  float* h1   = out + 3200000;       // (64, 512)
  float* c1   = h1 + 32768;          // (64, 512)
  float* nmem = c1 + 32768;          // (64, 128, 64)
  float* ncov = nmem + 524288;       // (64, 400)

  float* w = (float*)d_ws;
  float* xcat1 = w;                  // 65536   [embedded | h0]
  float* xcat2 = xcat1 + 65536;      // 65536   [embedded | attn_applied]
  float* xcat3 = xcat2 + 65536;      // 36864   [out0 | read_in]
  float* ia    = xcat3 + 36864;      // 25600
  float* ts    = ia + 25600;         // 25600
  float* tc    = ts + 25600;         // 25600
  float* aw    = tc + 25600;         // 25600
  float* U     = aw + 25600;         // 557056  shared: attn partials(524288) / pre partials(65536)
  float* pre_r = U + 557056;         // 4096
  float* pre_w = pre_r + 4096;       // 4096
  float* g_r   = pre_w + 4096;       // 66560
  float* g_w   = g_r + 66560;        // 66560
  float* rh    = g_w + 66560;        // 16640
  float* wh    = rh + 16640;         // 16640
  float* rw    = wh + 16640;         // 8192
  float* wwgt  = rw + 8192;          // 8192
  float* pm    = wwgt + 8192;        // 1600
  float* ps    = pm + 1600;          // 1600
  float* lse   = ps + 1600;          // 64
  unsigned short* c1b = (unsigned short*)(lse + 64);   // 32768 bf16 (16384 floats)

  // attention path
  k_embed<<<128, 256, 0, stream>>>(ids, emb, h0, xcat1, xcat2);
  k_gemv<1,0><<<dim3(100,64), 256, 0, stream>>>(xcat1, xcat1, attn_W, attn_b, ia, 1024, LL, LL);
  k_gemv<0,0><<<dim3(100,64), 256, 0, stream>>>(c0, c0, state_W, nullptr, ts, HH, LL, LL);
  k_cov<<<100, 256, 0, stream>>>(cov, ia, ncov);
  k_gemv<0,1><<<dim3(100,64), 256, 0, stream>>>(cov, ia, cov_W, nullptr, tc, LL, LL, LL);
  k_softmax_aw<<<64, 256, 0, stream>>>(ia, ts, tc, aw);
  k_attn_part<<<dim3(64,16), 256, 0, stream>>>(aw, enc, U);
  k_attn_reduce<<<128, 256, 0, stream>>>(U, xcat2);
  k_gemv<1,0><<<dim3(128,64), 256, 0, stream>>>(xcat2, xcat2, comb_W, comb_b, xcat3, 1024, HH, 576);

  // pre-projections (K=8704, 8-way K-split GEMV)
  k_pre_gemv<<<dim3(16,64,16), 256, 0, stream>>>(h0, mem, rpre_W, wpre_W, U);
  k_pre_reduce<<<32, 256, 0, stream>>>(U, rpre_b, wpre_b, pre_r, pre_w);

  // read/write head gates + LSTMs (fused)
  k_gates_rw<<<dim3(260,64,2), 256, 0, stream>>>(pre_r, pre_w, read_h, write_h,
      r_Wih, r_Whh, r_bih, r_bhh, w_Wih, w_Whh, w_bih, w_bhh, g_r, g_w);
  k_lstm_rw<<<130, 256, 0, stream>>>(g_r, g_w, read_c, write_c, rh, wh);

  // addressing + memory ops
  k_address<<<dim3(64,2), 128, 0, stream>>>(rh, wh, rheads, wheads, mem, rw, wwgt);
  k_readin<<<64, 64, 0, stream>>>(rw, mem, xcat3);
  k_newmem<<<2048, 256, 0, stream>>>(mem, wwgt, wh, nmem);

  // main LSTM (fused gates GEMV + elementwise, emits bf16 c1)
  k_lstm_main<<<dim3(128,64), 256, 0, stream>>>(xcat3, h0, l_Wih, l_Whh, l_bih, l_bhh,
                                                c0, h1, c1, c1b);

  // output projection (bf16 MFMA, deep W batch) + log_softmax
  k_logits_mfma<<<782, 256, 0, stream>>>(c1b, out_W, out_b, lp);
  k_ls1<<<dim3(25,64), 256, 0, stream>>>(lp, pm, ps);
  k_ls2<<<1, 64, 0, stream>>>(pm, ps, lse);
  k_ls3<<<12500, 256, 0, stream>>>(lp, lse);
}

// Round 5
// 511.153 us; speedup vs baseline: 1.0202x; 1.0023x over previous
//
#include <hip/hip_runtime.h>
#include <math.h>

#define BB 64
#define HH 512
#define VV 50000
#define LL 400
#define MM 128
#define DD 64
#define HC 260
#define EPSF 1e-8f

typedef __attribute__((ext_vector_type(8))) short bf16x8;
typedef __attribute__((ext_vector_type(4))) float f32x4;
typedef __attribute__((address_space(1))) const void CGV;   // global src for global_load_lds
typedef __attribute__((address_space(3))) void LV;          // lds dst for global_load_lds

__device__ __forceinline__ float sigmoidf(float x){ return 1.0f/(1.0f+expf(-x)); }
__device__ __forceinline__ unsigned short bf16_rne(float f){
  unsigned u = __float_as_uint(f);
  return (unsigned short)((u + 0x7fffu + ((u >> 16) & 1u)) >> 16);
}
__device__ __forceinline__ float wave_max(float v){
  #pragma unroll
  for(int o=32;o;o>>=1) v = fmaxf(v, __shfl_xor(v,o));
  return v;
}
__device__ __forceinline__ float wave_sum(float v){
  #pragma unroll
  for(int o=32;o;o>>=1) v += __shfl_xor(v,o);
  return v;
}

// ---------------- embed + concat builders ----------------
__global__ void k_embed(const int* __restrict__ ids, const float* __restrict__ emb,
                        const float* __restrict__ h0, float* __restrict__ xcat1,
                        float* __restrict__ xcat2){
  int idx = blockIdx.x*256 + threadIdx.x;           // 64*512
  if (idx >= BB*HH) return;
  int b = idx >> 9, h = idx & 511;
  float e = emb[(long)ids[b]*HH + h];
  xcat1[b*1024 + h] = e;
  xcat2[b*1024 + h] = e;
  xcat1[b*1024 + 512 + h] = h0[idx];
}

// ---------------- wave-per-output GEMV: C[b,n] = (A[+A2])[b,:] . W[n,:] ----------------
template<int NB, int FUSE>
__global__ __launch_bounds__(256) void k_gemv(const float* __restrict__ A,
                                              const float* __restrict__ A2,
                                              const float* __restrict__ W,
                                              const float* __restrict__ b1,
                                              float* __restrict__ C,
                                              int K, int N, int ldc){
  int b = blockIdx.y;
  int wid = threadIdx.x >> 6, lane = threadIdx.x & 63;
  int n = blockIdx.x*4 + wid;
  if (n >= N) return;
  const float4* A4  = (const float4*)(A + (long)b*K);
  const float4* A24 = (const float4*)(A2 + (long)b*K);
  const float4* W4  = (const float4*)(W + (long)n*K);
  int K4 = K >> 2;
  float acc = 0.f;
  for (int k = lane; k < K4; k += 64){
    float4 a = A4[k];
    if (FUSE){ float4 a2 = A24[k]; a.x+=a2.x; a.y+=a2.y; a.z+=a2.z; a.w+=a2.w; }
    float4 w = W4[k];
    acc += a.x*w.x + a.y*w.y + a.z*w.z + a.w*w.w;
  }
  acc = wave_sum(acc);
  if (lane == 0){
    if (NB) acc += b1[n];
    C[(long)b*ldc + n] = acc;
  }
}

// ---------------- new_coverage = coverage + ia ----------------
__global__ void k_cov(const float* __restrict__ cov, const float* __restrict__ ia,
                      float* __restrict__ out){
  int idx = blockIdx.x*256 + threadIdx.x;     // 25600
  if (idx >= BB*LL) return;
  out[idx] = cov[idx] + ia[idx];
}

// ---------------- aw = softmax(tc+ia+ts) over L ----------------
__global__ __launch_bounds__(256) void k_softmax_aw(const float* __restrict__ ia,
                                                    const float* __restrict__ ts,
                                                    const float* __restrict__ tc,
                                                    float* __restrict__ aw){
  int b = blockIdx.x, t = threadIdx.x;
  int i0 = t, i1 = t + 256;
  float x0 = ia[b*LL+i0] + ts[b*LL+i0] + tc[b*LL+i0];
  float x1 = (i1 < LL) ? (ia[b*LL+i1] + ts[b*LL+i1] + tc[b*LL+i1]) : -INFINITY;
  __shared__ float sm[4], ss[4];
  float m = wave_max(fmaxf(x0, x1));
  if ((t & 63) == 0) sm[t>>6] = m;
  __syncthreads();
  m = fmaxf(fmaxf(sm[0], sm[1]), fmaxf(sm[2], sm[3]));
  float e0 = expf(x0 - m);
  float e1 = (i1 < LL) ? expf(x1 - m) : 0.0f;
  float s = wave_sum(e0 + e1);
  if ((t & 63) == 0) ss[t>>6] = s;
  __syncthreads();
  float tot = ss[0] + ss[1] + ss[2] + ss[3];
  float inv = 1.0f / tot;
  aw[b*LL + i0] = e0 * inv;
  if (i1 < LL) aw[b*LL + i1] = e1 * inv;
}

// ---------------- attn_applied partials: grid (64 b, 16 l-chunks of 25) ----------------
__global__ __launch_bounds__(256) void k_attn_part(const float* __restrict__ aw,
                                                   const float* __restrict__ enc,
                                                   float* __restrict__ part){
  int b = blockIdx.x, lc = blockIdx.y, t = threadIdx.x;
  const float* awb = aw + b*LL + lc*25;
  const float* eb  = enc + ((long)b*LL + lc*25)*HH;
  float a0 = 0.f, a1 = 0.f;
  for (int l = 0; l < 25; l++){
    float a = awb[l];
    a0 += a * eb[(long)l*HH + t];
    a1 += a * eb[(long)l*HH + t + 256];
  }
  part[((b*16 + lc) << 9) + t]       = a0;
  part[((b*16 + lc) << 9) + t + 256] = a1;
}

__global__ void k_attn_reduce(const float* __restrict__ part, float* __restrict__ xcat2){
  int idx = blockIdx.x*256 + threadIdx.x;       // 64*512
  if (idx >= BB*HH) return;
  int b = idx >> 9, h = idx & 511;
  float s = 0.f;
  #pragma unroll
  for (int lc = 0; lc < 16; lc++) s += part[((b*16 + lc) << 9) + h];
  xcat2[b*1024 + 512 + h] = s;
}

// ---------------- pre GEMV, K-split: grid (16 n-quads, 64 b, which*8+chunk) ----------------
// pre = [h0 | mem] @ {r,w}pre_W^T ; K=8704 split into 8 chunks of 1088.
__global__ __launch_bounds__(256) void k_pre_gemv(const float* __restrict__ h0,
                                                  const float* __restrict__ mem,
                                                  const float* __restrict__ rW,
                                                  const float* __restrict__ wW,
                                                  float* __restrict__ part){
  int wid = threadIdx.x >> 6, lane = threadIdx.x & 63;
  int n = blockIdx.x*4 + wid;        // 0..63
  int b = blockIdx.y;
  int z = blockIdx.z;                // which*8 + chunk
  int which = z >> 3, chunk = z & 7;
  const float* W = which ? wW : rW;
  const float4* W4 = (const float4*)(W + (long)n*8704 + chunk*1088);
  const float4* H4 = (const float4*)(h0 + (long)b*HH);
  const float4* M4 = (const float4*)(mem + (long)b*8192 + (chunk*1088 - 512));
  float acc = 0.f;
  #pragma unroll
  for (int i = 0; i < 5; i++){
    int k4 = lane + i*64;            // float4 index within chunk (272 total)
    if (k4 < 272){
      int kg4 = chunk*272 + k4;      // global float4 index
      float4 a = (kg4 < 128) ? H4[kg4] : M4[k4];
      float4 w = W4[k4];
      acc += a.x*w.x + a.y*w.y + a.z*w.z + a.w*w.w;
    }
  }
  acc = wave_sum(acc);
  if (lane == 0) part[z*4096 + b*64 + n] = acc;
}

__global__ void k_pre_reduce(const float* __restrict__ part, const float* __restrict__ rb,
                             const float* __restrict__ wb, float* __restrict__ pre_r,
                             float* __restrict__ pre_w){
  int idx = blockIdx.x*256 + threadIdx.x;     // 8192
  if (idx >= 8192) return;
  int which = idx >> 12;
  int r = idx & 4095;
  float s = 0.f;
  #pragma unroll
  for (int c = 0; c < 8; c++) s += part[((which<<3)+c)*4096 + r];
  int n = r & 63;
  s += which ? wb[n] : rb[n];
  (which ? pre_w : pre_r)[r] = s;
}

// ---------------- fused gates GEMV for r/w heads: grid (260, 64, 2) ----------------
__global__ __launch_bounds__(256) void k_gates_rw(const float* __restrict__ pre_r,
    const float* __restrict__ pre_w, const float* __restrict__ read_h,
    const float* __restrict__ write_h,
    const float* __restrict__ rWih, const float* __restrict__ rWhh,
    const float* __restrict__ rbih, const float* __restrict__ rbhh,
    const float* __restrict__ wWih, const float* __restrict__ wWhh,
    const float* __restrict__ wbih, const float* __restrict__ wbhh,
    float* __restrict__ g_r, float* __restrict__ g_w){
  int which = blockIdx.z;
  int b = blockIdx.y;
  int wid = threadIdx.x >> 6, lane = threadIdx.x & 63;
  int n = blockIdx.x*4 + wid;     // < 1040
  const float* pre = which ? pre_w : pre_r;     // (64,64)
  const float* hh  = which ? write_h : read_h;  // (64,260)
  const float* Wih = which ? wWih : rWih;       // (1040,64)
  const float* Whh = which ? wWhh : rWhh;       // (1040,260)
  float acc = pre[b*64 + lane] * Wih[n*64 + lane];
  const float* hb = hh + b*HC;
  const float* wr = Whh + (long)n*HC;
  #pragma unroll
  for (int i = 0; i < 5; i++){
    int k = lane + i*64;
    if (k < HC) acc += hb[k]*wr[k];
  }
  acc = wave_sum(acc);
  if (lane == 0){
    acc += (which ? wbih : rbih)[n] + (which ? wbhh : rbhh)[n];
    (which ? g_w : g_r)[(long)b*4*HC + n] = acc;
  }
}

// ---------------- fused r+w LSTM elementwise ----------------
__global__ void k_lstm_rw(const float* __restrict__ g_r, const float* __restrict__ g_w,
                          const float* __restrict__ read_c, const float* __restrict__ write_c,
                          float* __restrict__ rh, float* __restrict__ wh){
  int idx = blockIdx.x*256 + threadIdx.x;    // 2*64*260 = 33280
  if (idx >= 2*BB*HC) return;
  int which = idx >= BB*HC;
  int r = which ? idx - BB*HC : idx;
  int b = r / HC, j = r - b*HC;
  const float* g = (which ? g_w : g_r) + (long)b*4*HC;
  float c2 = sigmoidf(g[HC + j]) * (which ? write_c : read_c)[r]
           + sigmoidf(g[j]) * tanhf(g[2*HC + j]);
  (which ? wh : rh)[r] = sigmoidf(g[3*HC + j]) * tanhf(c2);
}

// ---------------- addressing: grid (64, 2), 128 threads ----------------
__global__ __launch_bounds__(128) void k_address(const float* __restrict__ rh,
                                                 const float* __restrict__ whv,
                                                 const float* __restrict__ rheads,
                                                 const float* __restrict__ wheads,
                                                 const float* __restrict__ mem,
                                                 float* __restrict__ rwout,
                                                 float* __restrict__ wwout){
  int which = blockIdx.y;
  int b = blockIdx.x, m = threadIdx.x;
  const float* hc = which ? whv : rh;
  const float* heads0 = which ? wheads : rheads;
  float* wout = which ? wwout : rwout;
  const float* mr = mem + ((long)b*MM + m)*DD;
  float s = 0.f, q = 0.f;
  #pragma unroll 8
  for (int d = 0; d < DD; d++){ float v = mr[d]; s += v; q += v*v; }
  float key  = hc[b*HC + m];
  float kstr = expf(hc[b*HC + 64]);
  float gate = sigmoidf(hc[b*HC + 65]);
  float nk = fmaxf(fabsf(key)*8.0f, EPSF);
  float nm = fmaxf(sqrtf(q), EPSF);
  float z  = kstr * (key*s) / (nk*nm);
  __shared__ float sm[2], ss[2];
  float mx = wave_max(z);
  if ((m & 63) == 0) sm[m>>6] = mx;
  __syncthreads();
  mx = fmaxf(sm[0], sm[1]);
  float e = expf(z - mx);
  float w = wave_sum(e);
  if ((m & 63) == 0) ss[m>>6] = w;
  __syncthreads();
  float content = e / (ss[0] + ss[1]);
  wout[b*MM + m] = gate*content + (1.0f - gate)*heads0[m];   // heads[0]: batch-0 row broadcast
}

// ---------------- read_in -> xcat3[:,512:576] ----------------
__global__ void k_readin(const float* __restrict__ rw, const float* __restrict__ mem,
                         float* __restrict__ xcat3){
  int b = blockIdx.x, d = threadIdx.x;    // 64 threads
  float s = 0.f;
  for (int m = 0; m < MM; m++) s += rw[b*MM + m] * mem[((long)b*MM + m)*DD + d];
  xcat3[b*576 + 512 + d] = s;
}

// ---------------- new_memory ----------------
__global__ void k_newmem(const float* __restrict__ mem, const float* __restrict__ ww,
                         const float* __restrict__ wh, float* __restrict__ out){
  int idx = blockIdx.x*256 + threadIdx.x;    // 524288
  if (idx >= BB*MM*DD) return;
  int b = idx >> 13;
  int m = (idx & 8191) >> 6;
  float w0 = ww[b*MM + m];
  float we = sigmoidf(wh[b*HC + 68 + m]);
  float wa = sigmoidf(wh[b*HC + 132 + m]);
  out[idx] = mem[idx]*(1.0f - w0*we) + w0*wa;
}

// ---------------- main LSTM fused: wave per (b,j) computes 4 gate dots + elementwise ----
// grid (128 j-quads, 64 b), 256 threads (4 waves). Also emits c1 as bf16 (c1b).
__global__ __launch_bounds__(256) void k_lstm_main(const float* __restrict__ xcat3,
                                                   const float* __restrict__ h0,
                                                   const float* __restrict__ lWih,
                                                   const float* __restrict__ lWhh,
                                                   const float* __restrict__ bih,
                                                   const float* __restrict__ bhh,
                                                   const float* __restrict__ c0,
                                                   float* __restrict__ h1,
                                                   float* __restrict__ c1,
                                                   unsigned short* __restrict__ c1b){
  int wid = threadIdx.x >> 6, lane = threadIdx.x & 63;
  int j = blockIdx.x*4 + wid;        // 0..511
  int b = blockIdx.y;
  const float4* A1 = (const float4*)(xcat3 + (long)b*576);   // 144 f4
  const float4* A2 = (const float4*)(h0 + (long)b*HH);       // 128 f4
  float gv[4];
  #pragma unroll
  for (int g = 0; g < 4; g++){
    int n = g*HH + j;
    const float4* W1 = (const float4*)(lWih + (long)n*576);
    const float4* W2 = (const float4*)(lWhh + (long)n*HH);
    float s = 0.f;
    #pragma unroll
    for (int i = 0; i < 3; i++){
      int k = lane + i*64;
      if (k < 144){ float4 a = A1[k], w = W1[k]; s += a.x*w.x + a.y*w.y + a.z*w.z + a.w*w.w; }
    }
    #pragma unroll
    for (int i = 0; i < 2; i++){
      int k = lane + i*64;
      float4 a = A2[k], w = W2[k]; s += a.x*w.x + a.y*w.y + a.z*w.z + a.w*w.w;
    }
    gv[g] = wave_sum(s);
  }
  if (lane == 0){
    #pragma unroll
    for (int g = 0; g < 4; g++){ int n = g*HH + j; gv[g] += bih[n] + bhh[n]; }
    float c2 = sigmoidf(gv[1])*c0[b*HH + j] + sigmoidf(gv[0])*tanhf(gv[2]);
    h1[b*HH + j] = sigmoidf(gv[3])*tanhf(c2);
    c1[b*HH + j] = c2;
    c1b[b*HH + j] = bf16_rne(c2);
  }
}

// ---------------- logits: bf16 MFMA with global_load_lds W staging. --------------------
// C(64,50000) = c1b(64,512,bf16) @ out_W^T(fp32->bf16 on the fly) + bias
// Mapping: wave = one 16-n strip x all 64 m rows; 1563 blocks x 2 waves; waves fully
// independent (own 32 KB LDS half, NO __syncthreads, no cross-wave sharing).
// Latency model (Little's law): need ~6 KB in flight per CU to reach the per-CU HBM
// share; here each wave bursts its FULL 32 KB W tile via 32 global_load_lds dwordx4
// (zero VGPR cost), then ONE s_waitcnt vmcnt(0) before compute. 2 blocks/CU (LDS-bound)
// = 128 KB in flight per CU. The two concurrent blocks hide each other's wait phase.
// DMA linear order: instr ci (0..31), lane l=(q=l>>4, nl=l&15) writes LDS float
// [ci*256 + l*4 ..+4) = W[row strip*16+nl][col q*4 + (ci&7)*16 + (ci>>3)*128 ..+4).
// Read for k-step ks: row nl, cols ks*32+q*8..+8  ->  off = (ks*2+(q>>1))*256
// + (q&1)*128 + nl*4 (and +64 for the second float4); bank-balanced.
__global__ __launch_bounds__(128) void k_logits_mfma(const unsigned short* __restrict__ Ab,
                                                     const float* __restrict__ W,
                                                     const float* __restrict__ bias,
                                                     float* __restrict__ C){
  __shared__ float lds[16384];             // 64 KB: 2 waves x 8192 floats
  int wid = threadIdx.x >> 6, lane = threadIdx.x & 63;
  int strip = blockIdx.x*2 + wid;          // 3125 strips of 16 n
  if (strip >= 3125) return;
  int nl = lane & 15;                      // n offset within strip / m offset in frags
  int q  = lane >> 4;                      // k sub-group
  int n  = strip*16 + nl;
  const float* Wlane = W + (long)n*HH + q*4;   // per-lane global source
  int base = wid*8192;                         // this wave's LDS region (floats)

  #pragma unroll
  for (int ci = 0; ci < 32; ci++)
    __builtin_amdgcn_global_load_lds((CGV*)(Wlane + ci*16),
        (LV*)&lds[base + ci*256], 16, 0, 0);
  asm volatile("s_waitcnt vmcnt(0)" ::: "memory");
  __builtin_amdgcn_sched_barrier(0);

  const bf16x8* A0 = (const bf16x8*)Ab + (long)(0*16 + nl)*64 + q;
  const bf16x8* A1 = (const bf16x8*)Ab + (long)(1*16 + nl)*64 + q;
  const bf16x8* A2 = (const bf16x8*)Ab + (long)(2*16 + nl)*64 + q;
  const bf16x8* A3 = (const bf16x8*)Ab + (long)(3*16 + nl)*64 + q;
  f32x4 acc0 = {0.f,0.f,0.f,0.f}, acc1 = acc0, acc2 = acc0, acc3 = acc0;

  #pragma unroll
  for (int ks = 0; ks < 16; ks++){
    int off = base + (ks*2 + (q>>1))*256 + (q&1)*128 + nl*4;
    float4 w0 = *(const float4*)&lds[off];
    float4 w1 = *(const float4*)&lds[off + 64];
    bf16x8 bf;
    bf[0] = (short)bf16_rne(w0.x); bf[1] = (short)bf16_rne(w0.y);
    bf[2] = (short)bf16_rne(w0.z); bf[3] = (short)bf16_rne(w0.w);
    bf[4] = (short)bf16_rne(w1.x); bf[5] = (short)bf16_rne(w1.y);
    bf[6] = (short)bf16_rne(w1.z); bf[7] = (short)bf16_rne(w1.w);
    bf16x8 a0 = A0[ks*4];
    bf16x8 a1 = A1[ks*4];
    bf16x8 a2 = A2[ks*4];
    bf16x8 a3 = A3[ks*4];
    acc0 = __builtin_amdgcn_mfma_f32_16x16x32_bf16(a0, bf, acc0, 0, 0, 0);
    acc1 = __builtin_amdgcn_mfma_f32_16x16x32_bf16(a1, bf, acc1, 0, 0, 0);
    acc2 = __builtin_amdgcn_mfma_f32_16x16x32_bf16(a2, bf, acc2, 0, 0, 0);
    acc3 = __builtin_amdgcn_mfma_f32_16x16x32_bf16(a3, bf, acc3, 0, 0, 0);
  }
  float bv = bias[n];
  #pragma unroll
  for (int r = 0; r < 4; r++){
    int m = q*4 + r;
    C[(long)(m     )*VV + n] = acc0[r] + bv;
    C[(long)(m + 16)*VV + n] = acc1[r] + bv;
    C[(long)(m + 32)*VV + n] = acc2[r] + bv;
    C[(long)(m + 48)*VV + n] = acc3[r] + bv;
  }
}

// ---------------- 3-stage log_softmax over V ----------------
__global__ __launch_bounds__(256) void k_ls1(const float* __restrict__ lp,
                                             float* __restrict__ pm, float* __restrict__ ps){
  int b = blockIdx.y, c = blockIdx.x, t = threadIdx.x;   // grid (25, 64)
  const float* row = lp + (long)b*VV + c*2000;
  float mx = -INFINITY;
  for (int i = t; i < 2000; i += 256) mx = fmaxf(mx, row[i]);
  __shared__ float sm[4], ss[4];
  mx = wave_max(mx);
  if ((t & 63) == 0) sm[t>>6] = mx;
  __syncthreads();
  mx = fmaxf(fmaxf(sm[0], sm[1]), fmaxf(sm[2], sm[3]));
  float s = 0.f;
  for (int i = t; i < 2000; i += 256) s += expf(row[i] - mx);
  s = wave_sum(s);
  if ((t & 63) == 0) ss[t>>6] = s;
  __syncthreads();
  if (t == 0){ pm[b*25 + c] = mx; ps[b*25 + c] = ss[0]+ss[1]+ss[2]+ss[3]; }
}

__global__ void k_ls2(const float* __restrict__ pm, const float* __restrict__ ps,
                      float* __restrict__ lse){
  int b = threadIdx.x;    // 64
  float m = -INFINITY;
  for (int c = 0; c < 25; c++) m = fmaxf(m, pm[b*25 + c]);
  float s = 0.f;
  for (int c = 0; c < 25; c++) s += ps[b*25 + c]*expf(pm[b*25 + c] - m);
  lse[b] = m + logf(s);
}

__global__ void k_ls3(float* __restrict__ lp, const float* __restrict__ lse){
  int idx = blockIdx.x*256 + threadIdx.x;
  if (idx >= BB*VV) return;
  int b = idx / VV;
  lp[idx] -= lse[b];
}

extern "C" void kernel_launch(void* const* d_in, const int* in_sizes, int n_in,
                              void* d_out, int out_size, void* d_ws, size_t ws_size,
                              hipStream_t stream) {
  const int*   ids     = (const int*)  d_in[0];
  const float* h0      = (const float*)d_in[1];
  const float* c0      = (const float*)d_in[2];
  const float* enc     = (const float*)d_in[3];
  const float* cov     = (const float*)d_in[5];
  const float* mem     = (const float*)d_in[6];
  const float* rheads  = (const float*)d_in[7];
  const float* wheads  = (const float*)d_in[8];
  const float* read_h  = (const float*)d_in[9];
  const float* read_c  = (const float*)d_in[10];
  const float* write_h = (const float*)d_in[11];
  const float* write_c = (const float*)d_in[12];
  const float* emb     = (const float*)d_in[13];
  const float* attn_W  = (const float*)d_in[14];
  const float* attn_b  = (const float*)d_in[15];
  const float* cov_W   = (const float*)d_in[16];
  const float* state_W = (const float*)d_in[17];
  const float* comb_W  = (const float*)d_in[18];
  const float* comb_b  = (const float*)d_in[19];
  const float* rpre_W  = (const float*)d_in[20];
  const float* rpre_b  = (const float*)d_in[21];
  const float* wpre_W  = (const float*)d_in[22];
  const float* wpre_b  = (const float*)d_in[23];
  const float* r_Wih   = (const float*)d_in[24];
  const float* r_Whh   = (const float*)d_in[25];
  const float* r_bih   = (const float*)d_in[26];
  const float* r_bhh   = (const float*)d_in[27];
  const float* w_Wih   = (const float*)d_in[28];
  const float* w_Whh   = (const float*)d_in[29];
  const float* w_bih   = (const float*)d_in[30];
  const float* w_bhh   = (const float*)d_in[31];
  const float* l_Wih   = (const float*)d_in[32];
  const float* l_Whh   = (const float*)d_in[33];
  const float* l_bih   = (const float*)d_in[34];
  const float* l_bhh   = (const float*)d_in[35];
  const float* out_W   = (const float*)d_in[36];
  const float* out_b   = (const float*)d_in[37];

  float* out  = (float*)d_out;
  float* lp   = out;                 // (64, 50000)
  float* h1   = out + 3200000;       // (64, 512)
  float* c1   = h1 + 32768;          // (64, 512)
  float* nmem = c1 + 32768;          // (64, 128, 64)
  float* ncov = nmem + 524288;       // (64, 400)

  float* w = (float*)d_ws;
  float* xcat1 = w;                  // 65536   [embedded | h0]
  float* xcat2 = xcat1 + 65536;      // 65536   [embedded | attn_applied]
  float* xcat3 = xcat2 + 65536;      // 36864   [out0 | read_in]
  float* ia    = xcat3 + 36864;      // 25600
  float* ts    = ia + 25600;         // 25600
  float* tc    = ts + 25600;         // 25600
  float* aw    = tc + 25600;         // 25600
  float* U     = aw + 25600;         // 557056  shared: attn partials(524288) / pre partials(65536)
  float* pre_r = U + 557056;         // 4096
  float* pre_w = pre_r + 4096;       // 4096
  float* g_r   = pre_w + 4096;       // 66560
  float* g_w   = g_r + 66560;        // 66560
  float* rh    = g_w + 66560;        // 16640
  float* wh    = rh + 16640;         // 16640
  float* rw    = wh + 16640;         // 8192
  float* wwgt  = rw + 8192;          // 8192
  float* pm    = wwgt + 8192;        // 1600
  float* ps    = pm + 1600;          // 1600
  float* lse   = ps + 1600;          // 64
  unsigned short* c1b = (unsigned short*)(lse + 64);   // 32768 bf16 (16384 floats)

  // attention path
  k_embed<<<128, 256, 0, stream>>>(ids, emb, h0, xcat1, xcat2);
  k_gemv<1,0><<<dim3(100,64), 256, 0, stream>>>(xcat1, xcat1, attn_W, attn_b, ia, 1024, LL, LL);
  k_gemv<0,0><<<dim3(100,64), 256, 0, stream>>>(c0, c0, state_W, nullptr, ts, HH, LL, LL);
  k_cov<<<100, 256, 0, stream>>>(cov, ia, ncov);
  k_gemv<0,1><<<dim3(100,64), 256, 0, stream>>>(cov, ia, cov_W, nullptr, tc, LL, LL, LL);
  k_softmax_aw<<<64, 256, 0, stream>>>(ia, ts, tc, aw);
  k_attn_part<<<dim3(64,16), 256, 0, stream>>>(aw, enc, U);
  k_attn_reduce<<<128, 256, 0, stream>>>(U, xcat2);
  k_gemv<1,0><<<dim3(128,64), 256, 0, stream>>>(xcat2, xcat2, comb_W, comb_b, xcat3, 1024, HH, 576);

  // pre-projections (K=8704, 8-way K-split GEMV)
  k_pre_gemv<<<dim3(16,64,16), 256, 0, stream>>>(h0, mem, rpre_W, wpre_W, U);
  k_pre_reduce<<<32, 256, 0, stream>>>(U, rpre_b, wpre_b, pre_r, pre_w);

  // read/write head gates + LSTMs (fused)
  k_gates_rw<<<dim3(260,64,2), 256, 0, stream>>>(pre_r, pre_w, read_h, write_h,
      r_Wih, r_Whh, r_bih, r_bhh, w_Wih, w_Whh, w_bih, w_bhh, g_r, g_w);
  k_lstm_rw<<<130, 256, 0, stream>>>(g_r, g_w, read_c, write_c, rh, wh);

  // addressing + memory ops
  k_address<<<dim3(64,2), 128, 0, stream>>>(rh, wh, rheads, wheads, mem, rw, wwgt);
  k_readin<<<64, 64, 0, stream>>>(rw, mem, xcat3);
  k_newmem<<<2048, 256, 0, stream>>>(mem, wwgt, wh, nmem);

  // main LSTM (fused gates GEMV + elementwise, emits bf16 c1)
  k_lstm_main<<<dim3(128,64), 256, 0, stream>>>(xcat3, h0, l_Wih, l_Whh, l_bih, l_bhh,
                                                c0, h1, c1, c1b);

  // output projection (bf16 MFMA, burst LDS-staged W) + log_softmax
  k_logits_mfma<<<1563, 128, 0, stream>>>(c1b, out_W, out_b, lp);
  k_ls1<<<dim3(25,64), 256, 0, stream>>>(lp, pm, ps);
  k_ls2<<<1, 64, 0, stream>>>(pm, ps, lse);
  k_ls3<<<12500, 256, 0, stream>>>(lp, lse);
}

// Round 6
// 479.142 us; speedup vs baseline: 1.0884x; 1.0668x over previous
//
#include <hip/hip_runtime.h>
#include <math.h>

#define BB 64
#define HH 512
#define VV 50000
#define LL 400
#define MM 128
#define DD 64
#define HC 260
#define EPSF 1e-8f

typedef __attribute__((ext_vector_type(8))) short bf16x8;
typedef __attribute__((ext_vector_type(4))) float f32x4;
typedef __attribute__((address_space(1))) const void CGV;   // global src for global_load_lds
typedef __attribute__((address_space(3))) void LV;          // lds dst for global_load_lds

__device__ __forceinline__ float sigmoidf(float x){ return 1.0f/(1.0f+expf(-x)); }
__device__ __forceinline__ unsigned short bf16_rne(float f){
  unsigned u = __float_as_uint(f);
  return (unsigned short)((u + 0x7fffu + ((u >> 16) & 1u)) >> 16);
}
__device__ __forceinline__ float wave_max(float v){
  #pragma unroll
  for(int o=32;o;o>>=1) v = fmaxf(v, __shfl_xor(v,o));
  return v;
}
__device__ __forceinline__ float wave_sum(float v){
  #pragma unroll
  for(int o=32;o;o>>=1) v += __shfl_xor(v,o);
  return v;
}
__device__ __forceinline__ float dot4(float4 a, float4 w){
  return a.x*w.x + a.y*w.y + a.z*w.z + a.w*w.w;
}

// ---------------- [1] ia + ts fused GEMV. grid (200, 64) ----------------
// bx<100:  ia[b,n] = [emb[ids[b]] | h0[b]] . attn_W[n] + attn_b[n]   (K=1024)
// bx>=100: ts[b,n] = c0[b] . state_W[n]                              (K=512)
__global__ __launch_bounds__(256) void k_ia_ts(const int* __restrict__ ids,
    const float* __restrict__ emb, const float* __restrict__ h0,
    const float* __restrict__ c0, const float* __restrict__ attn_W,
    const float* __restrict__ attn_b, const float* __restrict__ state_W,
    float* __restrict__ ia, float* __restrict__ ts){
  int b = blockIdx.y;
  int wid = threadIdx.x >> 6, lane = threadIdx.x & 63;
  if (blockIdx.x < 100){
    int n = blockIdx.x*4 + wid;
    const float4* E4 = (const float4*)(emb + (long)ids[b]*HH);
    const float4* H4 = (const float4*)(h0 + (long)b*HH);
    const float4* W4 = (const float4*)(attn_W + (long)n*1024);
    float acc = 0.f;
    #pragma unroll
    for (int i = 0; i < 4; i++){
      int k = lane + i*64;                 // 0..255
      float4 a = (k < 128) ? E4[k] : H4[k-128];
      acc += dot4(a, W4[k]);
    }
    acc = wave_sum(acc);
    if (lane == 0) ia[b*LL + n] = acc + attn_b[n];
  } else {
    int n = (blockIdx.x-100)*4 + wid;
    const float4* A4 = (const float4*)(c0 + (long)b*HH);
    const float4* W4 = (const float4*)(state_W + (long)n*HH);
    float acc = 0.f;
    #pragma unroll
    for (int i = 0; i < 2; i++){
      int k = lane + i*64;                 // 0..127
      acc += dot4(A4[k], W4[k]);
    }
    acc = wave_sum(acc);
    if (lane == 0) ts[b*LL + n] = acc;
  }
}

// ---------------- [2] tc GEMV + ncov write. grid (100, 64) ----------------
// tc[b,n] = (cov+ia)[b] . cov_W[n];  ncov[b,n] = cov[b,n]+ia[b,n]
__global__ __launch_bounds__(256) void k_tc_cov(const float* __restrict__ cov,
    const float* __restrict__ ia, const float* __restrict__ cov_W,
    float* __restrict__ tc, float* __restrict__ ncov){
  int b = blockIdx.y;
  int wid = threadIdx.x >> 6, lane = threadIdx.x & 63;
  int n = blockIdx.x*4 + wid;
  const float4* C4 = (const float4*)(cov + (long)b*LL);
  const float4* I4 = (const float4*)(ia + (long)b*LL);
  const float4* W4 = (const float4*)(cov_W + (long)n*LL);
  float acc = 0.f;
  #pragma unroll
  for (int i = 0; i < 2; i++){
    int k = lane + i*64;
    if (k < 100){
      float4 a = C4[k], a2 = I4[k], w = W4[k];
      acc += (a.x+a2.x)*w.x + (a.y+a2.y)*w.y + (a.z+a2.z)*w.z + (a.w+a2.w)*w.w;
    }
  }
  acc = wave_sum(acc);
  if (lane == 0){
    tc[b*LL + n] = acc;
    ncov[b*LL + n] = cov[b*LL + n] + ia[b*LL + n];
  }
}

// ---------------- [3] attn partials with inline softmax. grid (64, 16) ----------------
// Each block recomputes the row softmax (cheap: 1.6KB x3 reads) then does its 25-l chunk.
__global__ __launch_bounds__(256) void k_attn_part(const float* __restrict__ ia,
                                                   const float* __restrict__ ts,
                                                   const float* __restrict__ tc,
                                                   const float* __restrict__ enc,
                                                   float* __restrict__ part){
  int b = blockIdx.x, lc = blockIdx.y, t = threadIdx.x;
  __shared__ float sh[400];
  __shared__ float sm[4], ss[4];
  int i0 = t, i1 = t + 256;
  float x0 = ia[b*LL+i0] + ts[b*LL+i0] + tc[b*LL+i0];
  float x1 = (i1 < LL) ? (ia[b*LL+i1] + ts[b*LL+i1] + tc[b*LL+i1]) : -INFINITY;
  float m = wave_max(fmaxf(x0, x1));
  if ((t & 63) == 0) sm[t>>6] = m;
  __syncthreads();
  m = fmaxf(fmaxf(sm[0], sm[1]), fmaxf(sm[2], sm[3]));
  float e0 = expf(x0 - m);
  float e1 = (i1 < LL) ? expf(x1 - m) : 0.0f;
  sh[i0] = e0;
  if (i1 < LL) sh[i1] = e1;
  float s = wave_sum(e0 + e1);
  if ((t & 63) == 0) ss[t>>6] = s;
  __syncthreads();
  float inv = 1.0f / (ss[0] + ss[1] + ss[2] + ss[3]);
  const float* eb = enc + ((long)b*LL + lc*25)*HH;
  float a0 = 0.f, a1 = 0.f;
  for (int l = 0; l < 25; l++){
    float a = sh[lc*25 + l] * inv;
    a0 += a * eb[(long)l*HH + t];
    a1 += a * eb[(long)l*HH + t + 256];
  }
  part[((b*16 + lc) << 9) + t]       = a0;
  part[((b*16 + lc) << 9) + t + 256] = a1;
}

// ---------------- [4] attn reduce -> attn(64,512) ----------------
__global__ void k_attn_reduce(const float* __restrict__ part, float* __restrict__ attn){
  int idx = blockIdx.x*256 + threadIdx.x;       // 64*512
  if (idx >= BB*HH) return;
  int b = idx >> 9, h = idx & 511;
  float s = 0.f;
  #pragma unroll
  for (int lc = 0; lc < 16; lc++) s += part[((b*16 + lc) << 9) + h];
  attn[b*HH + h] = s;
}

// ---------------- [5] comb GEMV -> xcat3[:, :512]. grid (128, 64) ----------------
// out0[b,n] = [emb[ids[b]] | attn[b]] . comb_W[n] + comb_b[n]   (K=1024)
__global__ __launch_bounds__(256) void k_comb(const int* __restrict__ ids,
    const float* __restrict__ emb, const float* __restrict__ attn,
    const float* __restrict__ comb_W, const float* __restrict__ comb_b,
    float* __restrict__ xcat3){
  int b = blockIdx.y;
  int wid = threadIdx.x >> 6, lane = threadIdx.x & 63;
  int n = blockIdx.x*4 + wid;                  // <512
  const float4* E4 = (const float4*)(emb + (long)ids[b]*HH);
  const float4* A4 = (const float4*)(attn + (long)b*HH);
  const float4* W4 = (const float4*)(comb_W + (long)n*1024);
  float acc = 0.f;
  #pragma unroll
  for (int i = 0; i < 4; i++){
    int k = lane + i*64;
    float4 a = (k < 128) ? E4[k] : A4[k-128];
    acc += dot4(a, W4[k]);
  }
  acc = wave_sum(acc);
  if (lane == 0) xcat3[b*576 + n] = acc + comb_b[n];
}

// ---------------- [6] pre GEMV full-K, wave per output. grid (16, 64, 2) ----------------
// pre_{r,w}[b,n] = [h0[b] | mem[b]] . {r,w}pre_W[n] + bias[n]     (K=8704)
__global__ __launch_bounds__(256) void k_pre(const float* __restrict__ h0,
    const float* __restrict__ mem, const float* __restrict__ rW,
    const float* __restrict__ wW, const float* __restrict__ rb,
    const float* __restrict__ wb, float* __restrict__ pre_r,
    float* __restrict__ pre_w){
  int wid = threadIdx.x >> 6, lane = threadIdx.x & 63;
  int n = blockIdx.x*4 + wid;        // 0..63
  int b = blockIdx.y;
  int which = blockIdx.z;
  const float* W = which ? wW : rW;
  const float4* W4 = (const float4*)(W + (long)n*8704);
  const float4* H4 = (const float4*)(h0 + (long)b*HH);
  const float4* M4 = (const float4*)(mem + (long)b*8192);
  float acc = 0.f;
  #pragma unroll 4
  for (int i = 0; i < 34; i++){
    int k = lane + i*64;             // 0..2175 (= 8704/4 - 1) exactly
    float4 a = (k < 128) ? H4[k] : M4[k-128];
    acc += dot4(a, W4[k]);
  }
  acc = wave_sum(acc);
  if (lane == 0) (which ? pre_w : pre_r)[b*64 + n] = acc + (which ? wb : rb)[n];
}

// ---------------- [7] gates + LSTM elementwise fused. grid (65, 64, 2) ----------------
// wave computes all 4 gate dots for unit j (K=64 pre + 260 h), lane0 applies LSTM.
__global__ __launch_bounds__(256) void k_gates(const float* __restrict__ pre_r,
    const float* __restrict__ pre_w, const float* __restrict__ read_h,
    const float* __restrict__ write_h, const float* __restrict__ read_c,
    const float* __restrict__ write_c,
    const float* __restrict__ rWih, const float* __restrict__ rWhh,
    const float* __restrict__ rbih, const float* __restrict__ rbhh,
    const float* __restrict__ wWih, const float* __restrict__ wWhh,
    const float* __restrict__ wbih, const float* __restrict__ wbhh,
    float* __restrict__ rh, float* __restrict__ wh){
  int which = blockIdx.z, b = blockIdx.y;
  int wid = threadIdx.x >> 6, lane = threadIdx.x & 63;
  int j = blockIdx.x*4 + wid;        // 0..259 exactly
  const float* pre = which ? pre_w : pre_r;
  const float* hhv = which ? write_h : read_h;
  const float* Wih = which ? wWih : rWih;      // (1040,64)
  const float* Whh = which ? wWhh : rWhh;      // (1040,260)
  float pv = pre[b*64 + lane];
  const float* hb = hhv + b*HC;
  float gv[4];
  #pragma unroll
  for (int g = 0; g < 4; g++){
    int n = g*HC + j;
    float acc = pv * Wih[n*64 + lane];
    const float* wr = Whh + (long)n*HC;
    #pragma unroll
    for (int i = 0; i < 5; i++){
      int k = lane + i*64;
      if (k < HC) acc += hb[k]*wr[k];
    }
    gv[g] = wave_sum(acc);
  }
  if (lane == 0){
    #pragma unroll
    for (int g = 0; g < 4; g++) gv[g] += (which ? wbih : rbih)[g*HC+j] + (which ? wbhh : rbhh)[g*HC+j];
    float c2 = sigmoidf(gv[1]) * (which ? write_c : read_c)[b*HC + j]
             + sigmoidf(gv[0]) * tanhf(gv[2]);
    (which ? wh : rh)[b*HC + j] = sigmoidf(gv[3]) * tanhf(c2);
  }
}

// ---------------- [8] addressing + read_in + new_memory fused. grid (64, 2) -----------
__global__ __launch_bounds__(128) void k_addr_mem(const float* __restrict__ rh,
                                                  const float* __restrict__ whv,
                                                  const float* __restrict__ rheads,
                                                  const float* __restrict__ wheads,
                                                  const float* __restrict__ mem,
                                                  float* __restrict__ xcat3,
                                                  float* __restrict__ nmem){
  int which = blockIdx.y;
  int b = blockIdx.x, m = threadIdx.x;
  const float* hc = which ? whv : rh;
  const float* heads0 = which ? wheads : rheads;
  const float* mr = mem + ((long)b*MM + m)*DD;
  float s = 0.f, q = 0.f;
  #pragma unroll 8
  for (int d = 0; d < DD; d++){ float v = mr[d]; s += v; q += v*v; }
  float key  = hc[b*HC + m];
  float kstr = expf(hc[b*HC + 64]);
  float gate = sigmoidf(hc[b*HC + 65]);
  float nk = fmaxf(fabsf(key)*8.0f, EPSF);
  float nm = fmaxf(sqrtf(q), EPSF);
  float z  = kstr * (key*s) / (nk*nm);
  __shared__ float sm[2], ss[2];
  __shared__ float wsh[128], weL[128], waL[128];
  float mx = wave_max(z);
  if ((m & 63) == 0) sm[m>>6] = mx;
  __syncthreads();
  mx = fmaxf(sm[0], sm[1]);
  float e = expf(z - mx);
  float w = wave_sum(e);
  if ((m & 63) == 0) ss[m>>6] = w;
  __syncthreads();
  float content = e / (ss[0] + ss[1]);
  float wv = gate*content + (1.0f - gate)*heads0[m];   // heads[0]: batch-0 row broadcast
  wsh[m] = wv;
  if (which){
    weL[m] = sigmoidf(whv[b*HC + 68 + m]);
    waL[m] = sigmoidf(whv[b*HC + 132 + m]);
  }
  __syncthreads();
  if (!which){
    // read_in -> xcat3[:, 512:576]
    if (m < DD){
      float acc = 0.f;
      #pragma unroll 8
      for (int mm = 0; mm < MM; mm++) acc += wsh[mm] * mem[((long)b*MM + mm)*DD + m];
      xcat3[b*576 + 512 + m] = acc;
    }
  } else {
    // new_memory
    for (int idx = m; idx < MM*DD; idx += 128){
      int mm = idx >> 6;
      nmem[(long)b*8192 + idx] = mem[(long)b*8192 + idx]*(1.0f - wsh[mm]*weL[mm]) + wsh[mm]*waL[mm];
    }
  }
}

// ---------------- [9] main LSTM fused (unchanged) ----------------
__global__ __launch_bounds__(256) void k_lstm_main(const float* __restrict__ xcat3,
                                                   const float* __restrict__ h0,
                                                   const float* __restrict__ lWih,
                                                   const float* __restrict__ lWhh,
                                                   const float* __restrict__ bih,
                                                   const float* __restrict__ bhh,
                                                   const float* __restrict__ c0,
                                                   float* __restrict__ h1,
                                                   float* __restrict__ c1,
                                                   unsigned short* __restrict__ c1b){
  int wid = threadIdx.x >> 6, lane = threadIdx.x & 63;
  int j = blockIdx.x*4 + wid;        // 0..511
  int b = blockIdx.y;
  const float4* A1 = (const float4*)(xcat3 + (long)b*576);   // 144 f4
  const float4* A2 = (const float4*)(h0 + (long)b*HH);       // 128 f4
  float gv[4];
  #pragma unroll
  for (int g = 0; g < 4; g++){
    int n = g*HH + j;
    const float4* W1 = (const float4*)(lWih + (long)n*576);
    const float4* W2 = (const float4*)(lWhh + (long)n*HH);
    float s = 0.f;
    #pragma unroll
    for (int i = 0; i < 3; i++){
      int k = lane + i*64;
      if (k < 144){ s += dot4(A1[k], W1[k]); }
    }
    #pragma unroll
    for (int i = 0; i < 2; i++){
      int k = lane + i*64;
      s += dot4(A2[k], W2[k]);
    }
    gv[g] = wave_sum(s);
  }
  if (lane == 0){
    #pragma unroll
    for (int g = 0; g < 4; g++){ int n = g*HH + j; gv[g] += bih[n] + bhh[n]; }
    float c2 = sigmoidf(gv[1])*c0[b*HH + j] + sigmoidf(gv[0])*tanhf(gv[2]);
    h1[b*HH + j] = sigmoidf(gv[3])*tanhf(c2);
    c1[b*HH + j] = c2;
    c1b[b*HH + j] = bf16_rne(c2);
  }
}

// ---------------- [10] logits: bf16 MFMA, burst global_load_lds W staging --------------
// (round-5 version, verified correct; 1563 blocks x 2 independent waves)
__global__ __launch_bounds__(128) void k_logits_mfma(const unsigned short* __restrict__ Ab,
                                                     const float* __restrict__ W,
                                                     const float* __restrict__ bias,
                                                     float* __restrict__ C){
  __shared__ float lds[16384];             // 64 KB: 2 waves x 8192 floats
  int wid = threadIdx.x >> 6, lane = threadIdx.x & 63;
  int strip = blockIdx.x*2 + wid;          // 3125 strips of 16 n
  if (strip >= 3125) return;
  int nl = lane & 15;
  int q  = lane >> 4;
  int n  = strip*16 + nl;
  const float* Wlane = W + (long)n*HH + q*4;
  int base = wid*8192;

  #pragma unroll
  for (int ci = 0; ci < 32; ci++)
    __builtin_amdgcn_global_load_lds((CGV*)(Wlane + ci*16),
        (LV*)&lds[base + ci*256], 16, 0, 0);
  asm volatile("s_waitcnt vmcnt(0)" ::: "memory");
  __builtin_amdgcn_sched_barrier(0);

  const bf16x8* A0 = (const bf16x8*)Ab + (long)(0*16 + nl)*64 + q;
  const bf16x8* A1 = (const bf16x8*)Ab + (long)(1*16 + nl)*64 + q;
  const bf16x8* A2 = (const bf16x8*)Ab + (long)(2*16 + nl)*64 + q;
  const bf16x8* A3 = (const bf16x8*)Ab + (long)(3*16 + nl)*64 + q;
  f32x4 acc0 = {0.f,0.f,0.f,0.f}, acc1 = acc0, acc2 = acc0, acc3 = acc0;

  #pragma unroll
  for (int ks = 0; ks < 16; ks++){
    int off = base + (ks*2 + (q>>1))*256 + (q&1)*128 + nl*4;
    float4 w0 = *(const float4*)&lds[off];
    float4 w1 = *(const float4*)&lds[off + 64];
    bf16x8 bf;
    bf[0] = (short)bf16_rne(w0.x); bf[1] = (short)bf16_rne(w0.y);
    bf[2] = (short)bf16_rne(w0.z); bf[3] = (short)bf16_rne(w0.w);
    bf[4] = (short)bf16_rne(w1.x); bf[5] = (short)bf16_rne(w1.y);
    bf[6] = (short)bf16_rne(w1.z); bf[7] = (short)bf16_rne(w1.w);
    bf16x8 a0 = A0[ks*4];
    bf16x8 a1 = A1[ks*4];
    bf16x8 a2 = A2[ks*4];
    bf16x8 a3 = A3[ks*4];
    acc0 = __builtin_amdgcn_mfma_f32_16x16x32_bf16(a0, bf, acc0, 0, 0, 0);
    acc1 = __builtin_amdgcn_mfma_f32_16x16x32_bf16(a1, bf, acc1, 0, 0, 0);
    acc2 = __builtin_amdgcn_mfma_f32_16x16x32_bf16(a2, bf, acc2, 0, 0, 0);
    acc3 = __builtin_amdgcn_mfma_f32_16x16x32_bf16(a3, bf, acc3, 0, 0, 0);
  }
  float bv = bias[n];
  #pragma unroll
  for (int r = 0; r < 4; r++){
    int m = q*4 + r;
    C[(long)(m     )*VV + n] = acc0[r] + bv;
    C[(long)(m + 16)*VV + n] = acc1[r] + bv;
    C[(long)(m + 32)*VV + n] = acc2[r] + bv;
    C[(long)(m + 48)*VV + n] = acc3[r] + bv;
  }
}

// ---------------- [11-13] 3-stage log_softmax over V (unchanged) ----------------
__global__ __launch_bounds__(256) void k_ls1(const float* __restrict__ lp,
                                             float* __restrict__ pm, float* __restrict__ ps){
  int b = blockIdx.y, c = blockIdx.x, t = threadIdx.x;   // grid (25, 64)
  const float* row = lp + (long)b*VV + c*2000;
  float mx = -INFINITY;
  for (int i = t; i < 2000; i += 256) mx = fmaxf(mx, row[i]);
  __shared__ float sm[4], ss[4];
  mx = wave_max(mx);
  if ((t & 63) == 0) sm[t>>6] = mx;
  __syncthreads();
  mx = fmaxf(fmaxf(sm[0], sm[1]), fmaxf(sm[2], sm[3]));
  float s = 0.f;
  for (int i = t; i < 2000; i += 256) s += expf(row[i] - mx);
  s = wave_sum(s);
  if ((t & 63) == 0) ss[t>>6] = s;
  __syncthreads();
  if (t == 0){ pm[b*25 + c] = mx; ps[b*25 + c] = ss[0]+ss[1]+ss[2]+ss[3]; }
}

__global__ void k_ls2(const float* __restrict__ pm, const float* __restrict__ ps,
                      float* __restrict__ lse){
  int b = threadIdx.x;    // 64
  float m = -INFINITY;
  for (int c = 0; c < 25; c++) m = fmaxf(m, pm[b*25 + c]);
  float s = 0.f;
  for (int c = 0; c < 25; c++) s += ps[b*25 + c]*expf(pm[b*25 + c] - m);
  lse[b] = m + logf(s);
}

__global__ void k_ls3(float* __restrict__ lp, const float* __restrict__ lse){
  int idx = blockIdx.x*256 + threadIdx.x;
  if (idx >= BB*VV) return;
  int b = idx / VV;
  lp[idx] -= lse[b];
}

extern "C" void kernel_launch(void* const* d_in, const int* in_sizes, int n_in,
                              void* d_out, int out_size, void* d_ws, size_t ws_size,
                              hipStream_t stream) {
  const int*   ids     = (const int*)  d_in[0];
  const float* h0      = (const float*)d_in[1];
  const float* c0      = (const float*)d_in[2];
  const float* enc     = (const float*)d_in[3];
  const float* cov     = (const float*)d_in[5];
  const float* mem     = (const float*)d_in[6];
  const float* rheads  = (const float*)d_in[7];
  const float* wheads  = (const float*)d_in[8];
  const float* read_h  = (const float*)d_in[9];
  const float* read_c  = (const float*)d_in[10];
  const float* write_h = (const float*)d_in[11];
  const float* write_c = (const float*)d_in[12];
  const float* emb     = (const float*)d_in[13];
  const float* attn_W  = (const float*)d_in[14];
  const float* attn_b  = (const float*)d_in[15];
  const float* cov_W   = (const float*)d_in[16];
  const float* state_W = (const float*)d_in[17];
  const float* comb_W  = (const float*)d_in[18];
  const float* comb_b  = (const float*)d_in[19];
  const float* rpre_W  = (const float*)d_in[20];
  const float* rpre_b  = (const float*)d_in[21];
  const float* wpre_W  = (const float*)d_in[22];
  const float* wpre_b  = (const float*)d_in[23];
  const float* r_Wih   = (const float*)d_in[24];
  const float* r_Whh   = (const float*)d_in[25];
  const float* r_bih   = (const float*)d_in[26];
  const float* r_bhh   = (const float*)d_in[27];
  const float* w_Wih   = (const float*)d_in[28];
  const float* w_Whh   = (const float*)d_in[29];
  const float* w_bih   = (const float*)d_in[30];
  const float* w_bhh   = (const float*)d_in[31];
  const float* l_Wih   = (const float*)d_in[32];
  const float* l_Whh   = (const float*)d_in[33];
  const float* l_bih   = (const float*)d_in[34];
  const float* l_bhh   = (const float*)d_in[35];
  const float* out_W   = (const float*)d_in[36];
  const float* out_b   = (const float*)d_in[37];

  float* out  = (float*)d_out;
  float* lp   = out;                 // (64, 50000)
  float* h1   = out + 3200000;       // (64, 512)
  float* c1   = h1 + 32768;          // (64, 512)
  float* nmem = c1 + 32768;          // (64, 128, 64)
  float* ncov = nmem + 524288;       // (64, 400)

  float* w = (float*)d_ws;
  float* xcat3 = w;                  // 36864   [out0 | read_in]
  float* ia    = xcat3 + 36864;      // 25600
  float* ts    = ia + 25600;         // 25600
  float* tc    = ts + 25600;         // 25600
  float* attn  = tc + 25600;         // 32768   attn_applied (64,512)
  float* U     = attn + 32768;       // 524288  attn partials
  float* pre_r = U + 524288;         // 4096
  float* pre_w = pre_r + 4096;       // 4096
  float* rh    = pre_w + 4096;       // 16640
  float* wh    = rh + 16640;         // 16640
  float* pm    = wh + 16640;         // 1600
  float* ps    = pm + 1600;          // 1600
  float* lse   = ps + 1600;          // 64
  unsigned short* c1b = (unsigned short*)(lse + 64);   // 32768 bf16

  // attention path (5 launches, was 9)
  k_ia_ts<<<dim3(200,64), 256, 0, stream>>>(ids, emb, h0, c0, attn_W, attn_b, state_W, ia, ts);
  k_tc_cov<<<dim3(100,64), 256, 0, stream>>>(cov, ia, cov_W, tc, ncov);
  k_attn_part<<<dim3(64,16), 256, 0, stream>>>(ia, ts, tc, enc, U);
  k_attn_reduce<<<128, 256, 0, stream>>>(U, attn);
  k_comb<<<dim3(128,64), 256, 0, stream>>>(ids, emb, attn, comb_W, comb_b, xcat3);

  // head path (3 launches, was 6)
  k_pre<<<dim3(16,64,2), 256, 0, stream>>>(h0, mem, rpre_W, wpre_W, rpre_b, wpre_b, pre_r, pre_w);
  k_gates<<<dim3(65,64,2), 256, 0, stream>>>(pre_r, pre_w, read_h, write_h, read_c, write_c,
      r_Wih, r_Whh, r_bih, r_bhh, w_Wih, w_Whh, w_bih, w_bhh, rh, wh);
  k_addr_mem<<<dim3(64,2), 128, 0, stream>>>(rh, wh, rheads, wheads, mem, xcat3, nmem);

  // main LSTM
  k_lstm_main<<<dim3(128,64), 256, 0, stream>>>(xcat3, h0, l_Wih, l_Whh, l_bih, l_bhh,
                                                c0, h1, c1, c1b);

  // output projection + log_softmax (4 launches)
  k_logits_mfma<<<1563, 128, 0, stream>>>(c1b, out_W, out_b, lp);
  k_ls1<<<dim3(25,64), 256, 0, stream>>>(lp, pm, ps);
  k_ls2<<<1, 64, 0, stream>>>(pm, ps, lse);
  k_ls3<<<12500, 256, 0, stream>>>(lp, lse);
}